// Round 21
// baseline (70.373 us; speedup 1.0000x reference)
//
#include <hip/hip_runtime.h>
#include <hip/hip_bf16.h>

typedef __attribute__((ext_vector_type(8))) short short8;
typedef __attribute__((ext_vector_type(4))) float f32x4;

#define MFMA16(a, b, c) __builtin_amdgcn_mfma_f32_16x16x32_bf16((a), (b), (c), 0, 0, 0)

// async global->LDS, 16B per lane; dest is wave-uniform base + lane*16
typedef const __attribute__((address_space(1))) unsigned int* gas_t;
typedef __attribute__((address_space(3))) unsigned int* las_t;
#define GLDS16(g, l) __builtin_amdgcn_global_load_lds((gas_t)(g), (las_t)(l), 16, 0, 0)

// scalar round-to-nearest-even f32 -> bf16 bits (proven rounds 1/3/6)
__device__ inline unsigned short f2bf(float f) {
    union { float f; unsigned int u; } v;
    v.f = f;
    unsigned int u = v.u;
    return (unsigned short)((u + 0x7fffu + ((u >> 16) & 1u)) >> 16);
}

__device__ inline float bf2f(unsigned short u) {
    union { unsigned int u; float f; } v;
    v.u = ((unsigned int)u) << 16;
    return v.f;
}

// ---------------------------------------------------------------------------
// FRAGMENT-ORDER LAYOUTS (proven round 18): for each (16-row tile, 32-col
// chunk) the 64 lanes' 16B fragments are stored contiguously -> one wave
// MFMA-operand load = ONE contiguous 1KB block.
// ---------------------------------------------------------------------------
__device__ inline size_t WF(int n, int c) {
    return ((((size_t)(n >> 4)) * 32 + (c >> 5)) * 64 + ((c >> 3) & 3) * 16 + (n & 15)) * 8 + (c & 7);
}
__device__ inline size_t QKF(int q, int h) {
    return ((((size_t)(q >> 4)) * 2 + (h >> 5)) * 64 + ((h >> 3) & 3) * 16 + (q & 15)) * 8 + (h & 7);
}
__device__ inline size_t VF(int h, int t) {
    return ((((size_t)(h >> 4)) * 128 + (t >> 5)) * 64 + ((t >> 3) & 3) * 16 + (h & 15)) * 8 + (t & 7);
}

// ---------------------------------------------------------------------------
// prep_w: Wt in fragment order. n in [0,192): 0..63 Wq (pre-scaled 1/8),
// 64..127 Wk, 128..191 Wv
// ---------------------------------------------------------------------------
__global__ __launch_bounds__(256) void prep_w(const float* __restrict__ Wq,
                                              const float* __restrict__ Wk,
                                              const float* __restrict__ Wv,
                                              unsigned short* __restrict__ Wt) {
    int idx = blockIdx.x * 256 + threadIdx.x;
    if (idx >= 192 * 1024) return;
    int n = idx >> 10;
    int c = idx & 1023;
    const float* W = (n < 64) ? Wq : ((n < 128) ? Wk : Wv);
    float v = W[c * 64 + (n & 63)];
    if (n < 64) v *= 0.125f;  // fold 1/sqrt(head_size) into Wq
    Wt[WF(n, c)] = f2bf(v);
}

// ---------------------------------------------------------------------------
// projt: WHOLE-TILE staged projection (r14 staging, r18 fragment-order W +
// epilogue). 1024 blocks x 4 waves, 2 blocks/CU. The entire 16x1024-f32
// x-tile (64 KB) is staged in ONE burst of 16 back-to-back global_load_lds
// per wave (128 KB/CU in flight -> full delivery rate), ONE barrier, then
// the whole compute phase is barrier-free: staging and W loads never
// interfere through vmcnt. Swizzle: within each 16-chunk window, LDS chunk
// = global chunk ^ row (both sides; r14-proven involution).
// ---------------------------------------------------------------------------
__global__ __launch_bounds__(256, 2) void projt(const float* __restrict__ x,
                                                const unsigned short* __restrict__ Wt,
                                                unsigned short* __restrict__ Qs,
                                                unsigned short* __restrict__ Ks,
                                                unsigned short* __restrict__ Vt) {
    __shared__ __align__(16) float xbuf[16 * 1024];  // 64 KB whole tile

    const int tid = threadIdx.x;
    const int w = tid >> 6;
    const int lane = tid & 63;
    const int lr = lane & 15;
    const int lg = lane >> 4;
    const int t0 = blockIdx.x * 16;

    // ---- stage whole x row-tile: wave w stages rows [w*4, w*4+4) ----
#pragma unroll
    for (int rr = 0; rr < 4; rr++) {
        int r = w * 4 + rr;
#pragma unroll
        for (int q = 0; q < 4; q++) {
            int gc = q * 64 + (lane >> 4) * 16 + ((lane & 15) ^ r);  // pre-swizzled src chunk
            const float* src = x + (size_t)(t0 + r) * 1024 + gc * 4;
            float* dst = &xbuf[r * 1024 + q * 256];  // wave-uniform, linear
            GLDS16(src, dst);
        }
    }
    __syncthreads();  // single drain; compute below is barrier-free

    f32x4 acc[3];
#pragma unroll
    for (int i = 0; i < 3; i++) acc[i] = (f32x4){0.f, 0.f, 0.f, 0.f};

    for (int t = 0; t < 8; ++t) {
        const int ch0 = t * 32;  // 16B-chunk base

        // batch this step's 12 fragment-order W loads (contiguous 1KB each)
        short8 bfr[4][3];
#pragma unroll
        for (int h = 0; h < 4; h++)
#pragma unroll
            for (int nt = 0; nt < 3; nt++)
                bfr[h][nt] = *(const short8*)(Wt +
                    (((size_t)(w * 3 + nt) * 32 + (t * 4 + h)) * 64 + lane) * 8);

#pragma unroll
        for (int h = 0; h < 4; h++) {
            int cb = ch0 + h * 8 + lg * 2;
            int l0 = (cb & ~15) | ((cb & 15) ^ lr);
            int l1 = ((cb + 1) & ~15) | (((cb + 1) & 15) ^ lr);
            float4 a0 = *(const float4*)&xbuf[lr * 1024 + l0 * 4];
            float4 a1 = *(const float4*)&xbuf[lr * 1024 + l1 * 4];
            short8 a;
            a[0] = (short)f2bf(a0.x); a[1] = (short)f2bf(a0.y);
            a[2] = (short)f2bf(a0.z); a[3] = (short)f2bf(a0.w);
            a[4] = (short)f2bf(a1.x); a[5] = (short)f2bf(a1.y);
            a[6] = (short)f2bf(a1.z); a[7] = (short)f2bf(a1.w);
#pragma unroll
            for (int nt = 0; nt < 3; nt++) acc[nt] = MFMA16(a, bfr[h][nt], acc[nt]);
        }
    }

    // epilogue: D col = lr -> n, row = lg*4+r -> t; fragment-order writes
    const int nbase = w * 48;
#pragma unroll
    for (int nt = 0; nt < 3; nt++) {
#pragma unroll
        for (int r = 0; r < 4; r++) {
            int n = nbase + nt * 16 + lr;
            int tq = t0 + lg * 4 + r;
            int b = tq >> 12;
            int qq = tq & 4095;
            unsigned short val = f2bf(acc[nt][r]);
            if (n < 64) {
                Qs[(size_t)b * 262144 + QKF(qq, n)] = val;
            } else if (n < 128) {
                Ks[(size_t)b * 262144 + QKF(qq, n - 64)] = val;
            } else {
                Vt[(size_t)b * 262144 + VF(n - 128, qq)] = val;
            }
        }
    }
}

// ---------------------------------------------------------------------------
// attn<NS>: causal flash attention, swapped QK^T (S^T = K*Q), QBLK=32,
// KVBLK=64, 1 wave/block, KV split into NS chunks. Barrier-free inner loop
// (single-wave blocks; lgkmcnt fence only). All Q/K/V loads are contiguous
// 1KB fragment-order wave-loads. (Identical to rounds 18/19.)
// ---------------------------------------------------------------------------
#define SROW 72  // P-tile row stride in halfwords (144 B/row)

template <int NS>
__global__ __launch_bounds__(64) void attn(const unsigned short* __restrict__ Qs,
                                           const unsigned short* __restrict__ Ks,
                                           const unsigned short* __restrict__ Vt,
                                           float* __restrict__ out,
                                           unsigned short* __restrict__ accP,
                                           float* __restrict__ mP,
                                           float* __restrict__ lP) {
    __shared__ unsigned short pl[32 * SROW];  // 32 q-rows x 64 kv-cols

    const int ntasks = 512 * NS;
    int raw = ntasks - 1 - blockIdx.x;  // longest scans first
    int qt_g = raw / NS;
    int c = raw - qt_g * NS;
    int qt = qt_g >> 2;
    int b = qt_g & 3;
    int q0 = qt * 32;

    int lane = threadIdx.x;
    int lr = lane & 15;
    int lg = lane >> 4;

    const unsigned short* Qb = Qs + (size_t)b * 262144;
    const unsigned short* Kb = Ks + (size_t)b * 262144;
    const unsigned short* Vb = Vt + (size_t)b * 262144;

    short8 qf[2][2];
#pragma unroll
    for (int qs = 0; qs < 2; qs++)
#pragma unroll
        for (int kh = 0; kh < 2; kh++)
            qf[qs][kh] = *(const short8*)(Qb +
                (((size_t)((q0 >> 4) + qs) * 2 + kh) * 64 + lane) * 8);

    f32x4 acc[4][2];  // [ht][qs]
#pragma unroll
    for (int i = 0; i < 4; i++)
#pragma unroll
        for (int qs = 0; qs < 2; qs++) acc[i][qs] = (f32x4){0.f, 0.f, 0.f, 0.f};
    float m[2] = {-1e30f, -1e30f};
    float l[2] = {0.f, 0.f};  // LANE-PARTIAL

    int nt = (q0 + 95) >> 6;  // ceil((q0+32)/64)
    int tb = (c * nt) / NS;
    int te = ((c + 1) * nt) / NS;

    // ---- preload K fragments for first tile ----
    short8 kf[4][2];
    if (tb < te) {
#pragma unroll
        for (int t = 0; t < 4; t++)
#pragma unroll
            for (int half = 0; half < 2; half++)
                kf[t][half] = *(const short8*)(Kb +
                    (((size_t)((tb * 64) >> 4) + t) * 2 + half) * 512 + lane * 8);
    }

    for (int t64 = tb; t64 < te; ++t64) {
        int kv0 = t64 * 64;

        // ---- S^T = K Q (consumes kf) ----
        f32x4 s[4][2];
#pragma unroll
        for (int t = 0; t < 4; t++)
#pragma unroll
            for (int qs = 0; qs < 2; qs++) {
                f32x4 z = (f32x4){0.f, 0.f, 0.f, 0.f};
                z = MFMA16(kf[t][0], qf[qs][0], z);
                z = MFMA16(kf[t][1], qf[qs][1], z);
                s[t][qs] = z;
            }

        // ---- issue V loads (contiguous 1KB each; in flight thru softmax) ----
        short8 vf[4][2];
#pragma unroll
        for (int ht = 0; ht < 4; ht++)
#pragma unroll
            for (int half = 0; half < 2; half++)
                vf[ht][half] = *(const short8*)(Vb +
                    (((size_t)ht * 128 + (kv0 >> 5) + half) * 64 + lane) * 8);

        // ---- reload kf for NEXT tile (latency hides under softmax+PV) ----
        if (t64 + 1 < te) {
            int kvn = (t64 + 1) * 64;
#pragma unroll
            for (int t = 0; t < 4; t++)
#pragma unroll
                for (int half = 0; half < 2; half++)
                    kf[t][half] = *(const short8*)(Kb +
                        (((size_t)(kvn >> 4) + t) * 2 + half) * 512 + lane * 8);
        }

        // ---- causal mask (only the straddling tile needs it) ----
        if (kv0 + 63 > q0) {
#pragma unroll
            for (int t = 0; t < 4; t++)
#pragma unroll
                for (int qs = 0; qs < 2; qs++)
#pragma unroll
                    for (int r = 0; r < 4; r++) {
                        int kv = kv0 + t * 16 + lg * 4 + r;
                        if (kv > q0 + qs * 16 + lr) s[t][qs][r] = -1e30f;
                    }
        }

        // ---- lane-local tile max (for defer-max check) ----
        float pmax[2] = {-1e30f, -1e30f};
#pragma unroll
        for (int t = 0; t < 4; t++)
#pragma unroll
            for (int qs = 0; qs < 2; qs++)
#pragma unroll
                for (int r = 0; r < 4; r++) pmax[qs] = fmaxf(pmax[qs], s[t][qs][r]);

        int ok = (pmax[0] <= m[0] + 8.0f) && (pmax[1] <= m[1] + 8.0f);
        if (!__all(ok)) {
            float alpha[2];
#pragma unroll
            for (int qs = 0; qs < 2; qs++) {
                float mx = pmax[qs];
                mx = fmaxf(mx, __shfl_xor(mx, 16));
                mx = fmaxf(mx, __shfl_xor(mx, 32));
                float mn = fmaxf(m[qs], mx);
                alpha[qs] = __expf(m[qs] - mn);
                m[qs] = mn;
                l[qs] *= alpha[qs];
            }
            float ar[2][4];
#pragma unroll
            for (int qs = 0; qs < 2; qs++)
#pragma unroll
                for (int r = 0; r < 4; r++) ar[qs][r] = __shfl(alpha[qs], lg * 4 + r);
#pragma unroll
            for (int ht = 0; ht < 4; ht++)
#pragma unroll
                for (int qs = 0; qs < 2; qs++)
#pragma unroll
                    for (int r = 0; r < 4; r++) acc[ht][qs][r] *= ar[qs][r];
        }

        // ---- exp + lane-partial l accumulation ----
#pragma unroll
        for (int t = 0; t < 4; t++)
#pragma unroll
            for (int qs = 0; qs < 2; qs++)
#pragma unroll
                for (int r = 0; r < 4; r++) {
                    float e = __expf(s[t][qs][r] - m[qs]);
                    s[t][qs][r] = e;
                    l[qs] += e;
                }

        // ---- pack P -> LDS (single-wave: lgkmcnt fence only, rule #18) ----
#pragma unroll
        for (int qs = 0; qs < 2; qs++)
#pragma unroll
            for (int t = 0; t < 4; t++) {
                uint2 uu;
                uu.x = (unsigned)f2bf(s[t][qs][0]) | ((unsigned)f2bf(s[t][qs][1]) << 16);
                uu.y = (unsigned)f2bf(s[t][qs][2]) | ((unsigned)f2bf(s[t][qs][3]) << 16);
                *(uint2*)&pl[(qs * 16 + lr) * SROW + t * 16 + lg * 4] = uu;
            }
        asm volatile("s_waitcnt lgkmcnt(0)" ::: "memory");
        __builtin_amdgcn_sched_barrier(0);
        short8 pa[2][2];
#pragma unroll
        for (int qs = 0; qs < 2; qs++)
#pragma unroll
            for (int half = 0; half < 2; half++)
                pa[qs][half] = *(const short8*)&pl[(qs * 16 + lr) * SROW +
                                                   half * 32 + lg * 8];

        // ---- O += P V ----
#pragma unroll
        for (int ht = 0; ht < 4; ht++)
#pragma unroll
            for (int qs = 0; qs < 2; qs++) {
                acc[ht][qs] = MFMA16(pa[qs][0], vf[ht][0], acc[ht][qs]);
                acc[ht][qs] = MFMA16(pa[qs][1], vf[ht][1], acc[ht][qs]);
            }
    }

    // ---- epilogue: reduce lane-partial l across the 4 lg groups ----
    float lt[2];
#pragma unroll
    for (int qs = 0; qs < 2; qs++) {
        float v = l[qs];
        v += __shfl_xor(v, 16);
        v += __shfl_xor(v, 32);
        lt[qs] = v;
    }

    if (NS == 1) {
        float rl[2][4];
#pragma unroll
        for (int qs = 0; qs < 2; qs++)
#pragma unroll
            for (int r = 0; r < 4; r++) rl[qs][r] = 1.0f / __shfl(lt[qs], lg * 4 + r);
#pragma unroll
        for (int ht = 0; ht < 4; ht++)
#pragma unroll
            for (int qs = 0; qs < 2; qs++)
#pragma unroll
                for (int r = 0; r < 4; r++) {
                    size_t o = ((size_t)b * 4096 + q0 + qs * 16 + lg * 4 + r) * 64 +
                               ht * 16 + lr;
                    out[o] = acc[ht][qs][r] * rl[qs][r];
                }
    } else {
        int tidx = qt_g * NS + c;
        unsigned short* ap = accP + (size_t)tidx * 2048;
#pragma unroll
        for (int ht = 0; ht < 4; ht++)
#pragma unroll
            for (int qs = 0; qs < 2; qs++)
#pragma unroll
                for (int r = 0; r < 4; r++)
                    ap[(qs * 16 + lg * 4 + r) * 64 + ht * 16 + lr] =
                        f2bf(acc[ht][qs][r]);
        if (lane < 16) {
#pragma unroll
            for (int qs = 0; qs < 2; qs++) {
                mP[tidx * 32 + qs * 16 + lane] = m[qs];
                lP[tidx * 32 + qs * 16 + lane] = lt[qs];
            }
        }
    }
}

// ---------------------------------------------------------------------------
// combine<NS>: out[row][h] = sum_c e^{m_c-M} acc_c / sum_c e^{m_c-M} l_c
// (bf16 partials)
// ---------------------------------------------------------------------------
template <int NS>
__global__ __launch_bounds__(256) void combine(const unsigned short* __restrict__ accP,
                                               const float* __restrict__ mP,
                                               const float* __restrict__ lP,
                                               float* __restrict__ out) {
    int g = blockIdx.x * 256 + threadIdx.x;  // 0 .. 1M-1
    int h = g & 63;
    int row = g >> 6;       // b*4096 + t
    int b = row >> 12;
    int t = row & 4095;
    int qt = t >> 5;
    int qr = t & 31;
    int qt_g = qt * 4 + b;

    float mc[NS];
    float M = -1e30f;
#pragma unroll
    for (int c = 0; c < NS; c++) {
        mc[c] = mP[(qt_g * NS + c) * 32 + qr];
        M = fmaxf(M, mc[c]);
    }
    float num = 0.f, den = 0.f;
#pragma unroll
    for (int c = 0; c < NS; c++) {
        float wgt = __expf(mc[c] - M);
        den += wgt * lP[(qt_g * NS + c) * 32 + qr];
        num += wgt * bf2f(accP[(size_t)(qt_g * NS + c) * 2048 + qr * 64 + h]);
    }
    out[g] = num / den;
}

// ---------------------------------------------------------------------------
extern "C" void kernel_launch(void* const* d_in, const int* in_sizes, int n_in,
                              void* d_out, int out_size, void* d_ws, size_t ws_size,
                              hipStream_t stream) {
    const float* x  = (const float*)d_in[0];
    const float* Wq = (const float*)d_in[1];
    const float* Wk = (const float*)d_in[2];
    const float* Wv = (const float*)d_in[3];
    float* out = (float*)d_out;

    char* ws = (char*)d_ws;
    unsigned short* Qs = (unsigned short*)(ws);                   // 2 MB @ 0
    unsigned short* Ks = (unsigned short*)(ws + (2u << 20));      // 2 MB @ 2M
    unsigned short* Vt = (unsigned short*)(ws + (4u << 20));      // 2 MB @ 4M
    unsigned short* Wt = (unsigned short*)(ws + (6u << 20));      // 384 KB @ 6M
    unsigned short* accP = (unsigned short*)(ws + (8u << 20));    // 16 MB @ 8M
    float* mP = (float*)(ws + (24u << 20));                       // 512 KB @ 24M
    float* lP = (float*)(ws + (24u << 20) + (512u << 10));        // 512 KB

    prep_w<<<768, 256, 0, stream>>>(Wq, Wk, Wv, Wt);
    projt<<<1024, 256, 0, stream>>>(x, Wt, Qs, Ks, Vt);

    if (ws_size >= (25u << 20)) {
        attn<8><<<4096, 64, 0, stream>>>(Qs, Ks, Vt, out, accP, mP, lP);
        combine<8><<<4096, 256, 0, stream>>>(accP, mP, lP, out);
    } else {
        attn<1><<<512, 64, 0, stream>>>(Qs, Ks, Vt, out, accP, mP, lP);
    }
}

// Round 22
// 69.763 us; speedup vs baseline: 1.0088x; 1.0088x over previous
//
#include <hip/hip_runtime.h>
#include <hip/hip_bf16.h>

typedef __attribute__((ext_vector_type(8))) short short8;
typedef __attribute__((ext_vector_type(4))) float f32x4;

#define MFMA16(a, b, c) __builtin_amdgcn_mfma_f32_16x16x32_bf16((a), (b), (c), 0, 0, 0)

// async global->LDS, 16B per lane; dest is wave-uniform base + lane*16
typedef const __attribute__((address_space(1))) unsigned int* gas_t;
typedef __attribute__((address_space(3))) unsigned int* las_t;
#define GLDS16(g, l) __builtin_amdgcn_global_load_lds((gas_t)(g), (las_t)(l), 16, 0, 0)

// scalar round-to-nearest-even f32 -> bf16 bits (proven rounds 1/3/6)
__device__ inline unsigned short f2bf(float f) {
    union { float f; unsigned int u; } v;
    v.f = f;
    unsigned int u = v.u;
    return (unsigned short)((u + 0x7fffu + ((u >> 16) & 1u)) >> 16);
}

__device__ inline float bf2f(unsigned short u) {
    union { unsigned int u; float f; } v;
    v.u = ((unsigned int)u) << 16;
    return v.f;
}

// ---------------------------------------------------------------------------
// FRAGMENT-ORDER LAYOUTS (proven round 18): for each (16-row tile, 32-col
// chunk) the 64 lanes' 16B fragments are stored contiguously -> one wave
// MFMA-operand load = ONE contiguous 1KB block.
// ---------------------------------------------------------------------------
__device__ inline size_t WF(int n, int c) {
    return ((((size_t)(n >> 4)) * 32 + (c >> 5)) * 64 + ((c >> 3) & 3) * 16 + (n & 15)) * 8 + (c & 7);
}
__device__ inline size_t QKF(int q, int h) {
    return ((((size_t)(q >> 4)) * 2 + (h >> 5)) * 64 + ((h >> 3) & 3) * 16 + (q & 15)) * 8 + (h & 7);
}
__device__ inline size_t VF(int h, int t) {
    return ((((size_t)(h >> 4)) * 128 + (t >> 5)) * 64 + ((t >> 3) & 3) * 16 + (h & 15)) * 8 + (t & 7);
}

// ---------------------------------------------------------------------------
// prep_w: Wt in fragment order. n in [0,192): 0..63 Wq (pre-scaled 1/8),
// 64..127 Wk, 128..191 Wv
// ---------------------------------------------------------------------------
__global__ __launch_bounds__(256) void prep_w(const float* __restrict__ Wq,
                                              const float* __restrict__ Wk,
                                              const float* __restrict__ Wv,
                                              unsigned short* __restrict__ Wt) {
    int idx = blockIdx.x * 256 + threadIdx.x;
    if (idx >= 192 * 1024) return;
    int n = idx >> 10;
    int c = idx & 1023;
    const float* W = (n < 64) ? Wq : ((n < 128) ? Wk : Wv);
    float v = W[c * 64 + (n & 63)];
    if (n < 64) v *= 0.125f;  // fold 1/sqrt(head_size) into Wq
    Wt[WF(n, c)] = f2bf(v);
}

// ---------------------------------------------------------------------------
// projt: WHOLE-TILE staged projection (r21; empirical floor ~39 us across
// five staging structures -- delivery-rate capped). 1024 blocks x 4 waves.
// ---------------------------------------------------------------------------
__global__ __launch_bounds__(256, 2) void projt(const float* __restrict__ x,
                                                const unsigned short* __restrict__ Wt,
                                                unsigned short* __restrict__ Qs,
                                                unsigned short* __restrict__ Ks,
                                                unsigned short* __restrict__ Vt) {
    __shared__ __align__(16) float xbuf[16 * 1024];  // 64 KB whole tile

    const int tid = threadIdx.x;
    const int w = tid >> 6;
    const int lane = tid & 63;
    const int lr = lane & 15;
    const int lg = lane >> 4;
    const int t0 = blockIdx.x * 16;

    // ---- stage whole x row-tile: wave w stages rows [w*4, w*4+4) ----
#pragma unroll
    for (int rr = 0; rr < 4; rr++) {
        int r = w * 4 + rr;
#pragma unroll
        for (int q = 0; q < 4; q++) {
            int gc = q * 64 + (lane >> 4) * 16 + ((lane & 15) ^ r);  // pre-swizzled src chunk
            const float* src = x + (size_t)(t0 + r) * 1024 + gc * 4;
            float* dst = &xbuf[r * 1024 + q * 256];  // wave-uniform, linear
            GLDS16(src, dst);
        }
    }
    __syncthreads();  // single drain; compute below is barrier-free

    f32x4 acc[3];
#pragma unroll
    for (int i = 0; i < 3; i++) acc[i] = (f32x4){0.f, 0.f, 0.f, 0.f};

    for (int t = 0; t < 8; ++t) {
        const int ch0 = t * 32;  // 16B-chunk base

        // batch this step's 12 fragment-order W loads (contiguous 1KB each)
        short8 bfr[4][3];
#pragma unroll
        for (int h = 0; h < 4; h++)
#pragma unroll
            for (int nt = 0; nt < 3; nt++)
                bfr[h][nt] = *(const short8*)(Wt +
                    (((size_t)(w * 3 + nt) * 32 + (t * 4 + h)) * 64 + lane) * 8);

#pragma unroll
        for (int h = 0; h < 4; h++) {
            int cb = ch0 + h * 8 + lg * 2;
            int l0 = (cb & ~15) | ((cb & 15) ^ lr);
            int l1 = ((cb + 1) & ~15) | (((cb + 1) & 15) ^ lr);
            float4 a0 = *(const float4*)&xbuf[lr * 1024 + l0 * 4];
            float4 a1 = *(const float4*)&xbuf[lr * 1024 + l1 * 4];
            short8 a;
            a[0] = (short)f2bf(a0.x); a[1] = (short)f2bf(a0.y);
            a[2] = (short)f2bf(a0.z); a[3] = (short)f2bf(a0.w);
            a[4] = (short)f2bf(a1.x); a[5] = (short)f2bf(a1.y);
            a[6] = (short)f2bf(a1.z); a[7] = (short)f2bf(a1.w);
#pragma unroll
            for (int nt = 0; nt < 3; nt++) acc[nt] = MFMA16(a, bfr[h][nt], acc[nt]);
        }
    }

    // epilogue: D col = lr -> n, row = lg*4+r -> t; fragment-order writes
    const int nbase = w * 48;
#pragma unroll
    for (int nt = 0; nt < 3; nt++) {
#pragma unroll
        for (int r = 0; r < 4; r++) {
            int n = nbase + nt * 16 + lr;
            int tq = t0 + lg * 4 + r;
            int b = tq >> 12;
            int qq = tq & 4095;
            unsigned short val = f2bf(acc[nt][r]);
            if (n < 64) {
                Qs[(size_t)b * 262144 + QKF(qq, n)] = val;
            } else if (n < 128) {
                Ks[(size_t)b * 262144 + QKF(qq, n - 64)] = val;
            } else {
                Vt[(size_t)b * 262144 + VF(n - 128, qq)] = val;
            }
        }
    }
}

// ---------------------------------------------------------------------------
// attn<NS>: causal flash attention, swapped QK^T (S^T = K*Q), QBLK=32,
// KVBLK=64, 1 wave/block, KV split into NS chunks. Barrier-free inner loop
// (single-wave blocks; lgkmcnt fence only). All Q/K/V loads are contiguous
// 1KB fragment-order wave-loads. (Identical to rounds 18-21.)
// ---------------------------------------------------------------------------
#define SROW 72  // P-tile row stride in halfwords (144 B/row)

template <int NS>
__global__ __launch_bounds__(64) void attn(const unsigned short* __restrict__ Qs,
                                           const unsigned short* __restrict__ Ks,
                                           const unsigned short* __restrict__ Vt,
                                           float* __restrict__ out,
                                           unsigned short* __restrict__ accP,
                                           float* __restrict__ mP,
                                           float* __restrict__ lP) {
    __shared__ unsigned short pl[32 * SROW];  // 32 q-rows x 64 kv-cols

    const int ntasks = 512 * NS;
    int raw = ntasks - 1 - blockIdx.x;  // longest scans first
    int qt_g = raw / NS;
    int c = raw - qt_g * NS;
    int qt = qt_g >> 2;
    int b = qt_g & 3;
    int q0 = qt * 32;

    int lane = threadIdx.x;
    int lr = lane & 15;
    int lg = lane >> 4;

    const unsigned short* Qb = Qs + (size_t)b * 262144;
    const unsigned short* Kb = Ks + (size_t)b * 262144;
    const unsigned short* Vb = Vt + (size_t)b * 262144;

    short8 qf[2][2];
#pragma unroll
    for (int qs = 0; qs < 2; qs++)
#pragma unroll
        for (int kh = 0; kh < 2; kh++)
            qf[qs][kh] = *(const short8*)(Qb +
                (((size_t)((q0 >> 4) + qs) * 2 + kh) * 64 + lane) * 8);

    f32x4 acc[4][2];  // [ht][qs]
#pragma unroll
    for (int i = 0; i < 4; i++)
#pragma unroll
        for (int qs = 0; qs < 2; qs++) acc[i][qs] = (f32x4){0.f, 0.f, 0.f, 0.f};
    float m[2] = {-1e30f, -1e30f};
    float l[2] = {0.f, 0.f};  // LANE-PARTIAL

    int nt = (q0 + 95) >> 6;  // ceil((q0+32)/64)
    int tb = (c * nt) / NS;
    int te = ((c + 1) * nt) / NS;

    // ---- preload K fragments for first tile ----
    short8 kf[4][2];
    if (tb < te) {
#pragma unroll
        for (int t = 0; t < 4; t++)
#pragma unroll
            for (int half = 0; half < 2; half++)
                kf[t][half] = *(const short8*)(Kb +
                    (((size_t)((tb * 64) >> 4) + t) * 2 + half) * 512 + lane * 8);
    }

    for (int t64 = tb; t64 < te; ++t64) {
        int kv0 = t64 * 64;

        // ---- S^T = K Q (consumes kf) ----
        f32x4 s[4][2];
#pragma unroll
        for (int t = 0; t < 4; t++)
#pragma unroll
            for (int qs = 0; qs < 2; qs++) {
                f32x4 z = (f32x4){0.f, 0.f, 0.f, 0.f};
                z = MFMA16(kf[t][0], qf[qs][0], z);
                z = MFMA16(kf[t][1], qf[qs][1], z);
                s[t][qs] = z;
            }

        // ---- issue V loads (contiguous 1KB each; in flight thru softmax) ----
        short8 vf[4][2];
#pragma unroll
        for (int ht = 0; ht < 4; ht++)
#pragma unroll
            for (int half = 0; half < 2; half++)
                vf[ht][half] = *(const short8*)(Vb +
                    (((size_t)ht * 128 + (kv0 >> 5) + half) * 64 + lane) * 8);

        // ---- reload kf for NEXT tile (latency hides under softmax+PV) ----
        if (t64 + 1 < te) {
            int kvn = (t64 + 1) * 64;
#pragma unroll
            for (int t = 0; t < 4; t++)
#pragma unroll
                for (int half = 0; half < 2; half++)
                    kf[t][half] = *(const short8*)(Kb +
                        (((size_t)(kvn >> 4) + t) * 2 + half) * 512 + lane * 8);
        }

        // ---- causal mask (only the straddling tile needs it) ----
        if (kv0 + 63 > q0) {
#pragma unroll
            for (int t = 0; t < 4; t++)
#pragma unroll
                for (int qs = 0; qs < 2; qs++)
#pragma unroll
                    for (int r = 0; r < 4; r++) {
                        int kv = kv0 + t * 16 + lg * 4 + r;
                        if (kv > q0 + qs * 16 + lr) s[t][qs][r] = -1e30f;
                    }
        }

        // ---- lane-local tile max (for defer-max check) ----
        float pmax[2] = {-1e30f, -1e30f};
#pragma unroll
        for (int t = 0; t < 4; t++)
#pragma unroll
            for (int qs = 0; qs < 2; qs++)
#pragma unroll
                for (int r = 0; r < 4; r++) pmax[qs] = fmaxf(pmax[qs], s[t][qs][r]);

        int ok = (pmax[0] <= m[0] + 8.0f) && (pmax[1] <= m[1] + 8.0f);
        if (!__all(ok)) {
            float alpha[2];
#pragma unroll
            for (int qs = 0; qs < 2; qs++) {
                float mx = pmax[qs];
                mx = fmaxf(mx, __shfl_xor(mx, 16));
                mx = fmaxf(mx, __shfl_xor(mx, 32));
                float mn = fmaxf(m[qs], mx);
                alpha[qs] = __expf(m[qs] - mn);
                m[qs] = mn;
                l[qs] *= alpha[qs];
            }
            float ar[2][4];
#pragma unroll
            for (int qs = 0; qs < 2; qs++)
#pragma unroll
                for (int r = 0; r < 4; r++) ar[qs][r] = __shfl(alpha[qs], lg * 4 + r);
#pragma unroll
            for (int ht = 0; ht < 4; ht++)
#pragma unroll
                for (int qs = 0; qs < 2; qs++)
#pragma unroll
                    for (int r = 0; r < 4; r++) acc[ht][qs][r] *= ar[qs][r];
        }

        // ---- exp + lane-partial l accumulation ----
#pragma unroll
        for (int t = 0; t < 4; t++)
#pragma unroll
            for (int qs = 0; qs < 2; qs++)
#pragma unroll
                for (int r = 0; r < 4; r++) {
                    float e = __expf(s[t][qs][r] - m[qs]);
                    s[t][qs][r] = e;
                    l[qs] += e;
                }

        // ---- pack P -> LDS (single-wave: lgkmcnt fence only, rule #18) ----
#pragma unroll
        for (int qs = 0; qs < 2; qs++)
#pragma unroll
            for (int t = 0; t < 4; t++) {
                uint2 uu;
                uu.x = (unsigned)f2bf(s[t][qs][0]) | ((unsigned)f2bf(s[t][qs][1]) << 16);
                uu.y = (unsigned)f2bf(s[t][qs][2]) | ((unsigned)f2bf(s[t][qs][3]) << 16);
                *(uint2*)&pl[(qs * 16 + lr) * SROW + t * 16 + lg * 4] = uu;
            }
        asm volatile("s_waitcnt lgkmcnt(0)" ::: "memory");
        __builtin_amdgcn_sched_barrier(0);
        short8 pa[2][2];
#pragma unroll
        for (int qs = 0; qs < 2; qs++)
#pragma unroll
            for (int half = 0; half < 2; half++)
                pa[qs][half] = *(const short8*)&pl[(qs * 16 + lr) * SROW +
                                                   half * 32 + lg * 8];

        // ---- O += P V ----
#pragma unroll
        for (int ht = 0; ht < 4; ht++)
#pragma unroll
            for (int qs = 0; qs < 2; qs++) {
                acc[ht][qs] = MFMA16(pa[qs][0], vf[ht][0], acc[ht][qs]);
                acc[ht][qs] = MFMA16(pa[qs][1], vf[ht][1], acc[ht][qs]);
            }
    }

    // ---- epilogue: reduce lane-partial l across the 4 lg groups ----
    float lt[2];
#pragma unroll
    for (int qs = 0; qs < 2; qs++) {
        float v = l[qs];
        v += __shfl_xor(v, 16);
        v += __shfl_xor(v, 32);
        lt[qs] = v;
    }

    if (NS == 1) {
        float rl[2][4];
#pragma unroll
        for (int qs = 0; qs < 2; qs++)
#pragma unroll
            for (int r = 0; r < 4; r++) rl[qs][r] = 1.0f / __shfl(lt[qs], lg * 4 + r);
#pragma unroll
        for (int ht = 0; ht < 4; ht++)
#pragma unroll
            for (int qs = 0; qs < 2; qs++)
#pragma unroll
                for (int r = 0; r < 4; r++) {
                    size_t o = ((size_t)b * 4096 + q0 + qs * 16 + lg * 4 + r) * 64 +
                               ht * 16 + lr;
                    out[o] = acc[ht][qs][r] * rl[qs][r];
                }
    } else {
        int tidx = qt_g * NS + c;
        unsigned short* ap = accP + (size_t)tidx * 2048;
#pragma unroll
        for (int ht = 0; ht < 4; ht++)
#pragma unroll
            for (int qs = 0; qs < 2; qs++)
#pragma unroll
                for (int r = 0; r < 4; r++)
                    ap[(qs * 16 + lg * 4 + r) * 64 + ht * 16 + lr] =
                        f2bf(acc[ht][qs][r]);
        if (lane < 16) {
#pragma unroll
            for (int qs = 0; qs < 2; qs++) {
                mP[tidx * 32 + qs * 16 + lane] = m[qs];
                lP[tidx * 32 + qs * 16 + lane] = lt[qs];
            }
        }
    }
}

// ---------------------------------------------------------------------------
// combine<NS>: out[row][h] = sum_c e^{m_c-M} acc_c / sum_c e^{m_c-M} l_c
// (bf16 partials)
// ---------------------------------------------------------------------------
template <int NS>
__global__ __launch_bounds__(256) void combine(const unsigned short* __restrict__ accP,
                                               const float* __restrict__ mP,
                                               const float* __restrict__ lP,
                                               float* __restrict__ out) {
    int g = blockIdx.x * 256 + threadIdx.x;  // 0 .. 1M-1
    int h = g & 63;
    int row = g >> 6;       // b*4096 + t
    int b = row >> 12;
    int t = row & 4095;
    int qt = t >> 5;
    int qr = t & 31;
    int qt_g = qt * 4 + b;

    float mc[NS];
    float M = -1e30f;
#pragma unroll
    for (int c = 0; c < NS; c++) {
        mc[c] = mP[(qt_g * NS + c) * 32 + qr];
        M = fmaxf(M, mc[c]);
    }
    float num = 0.f, den = 0.f;
#pragma unroll
    for (int c = 0; c < NS; c++) {
        float wgt = __expf(mc[c] - M);
        den += wgt * lP[(qt_g * NS + c) * 32 + qr];
        num += wgt * bf2f(accP[(size_t)(qt_g * NS + c) * 2048 + qr * 64 + h]);
    }
    out[g] = num / den;
}

// ---------------------------------------------------------------------------
extern "C" void kernel_launch(void* const* d_in, const int* in_sizes, int n_in,
                              void* d_out, int out_size, void* d_ws, size_t ws_size,
                              hipStream_t stream) {
    const float* x  = (const float*)d_in[0];
    const float* Wq = (const float*)d_in[1];
    const float* Wk = (const float*)d_in[2];
    const float* Wv = (const float*)d_in[3];
    float* out = (float*)d_out;

    char* ws = (char*)d_ws;
    unsigned short* Qs = (unsigned short*)(ws);                   // 2 MB @ 0
    unsigned short* Ks = (unsigned short*)(ws + (2u << 20));      // 2 MB @ 2M
    unsigned short* Vt = (unsigned short*)(ws + (4u << 20));      // 2 MB @ 4M
    unsigned short* Wt = (unsigned short*)(ws + (6u << 20));      // 384 KB @ 6M
    unsigned short* accP = (unsigned short*)(ws + (8u << 20));    // 8 MB @ 8M (2048 tasks x 4KB bf16)
    float* mP = (float*)(ws + (24u << 20));                       // 256 KB @ 24M
    float* lP = (float*)(ws + (24u << 20) + (512u << 10));        // 256 KB

    prep_w<<<768, 256, 0, stream>>>(Wq, Wk, Wv, Wt);
    projt<<<1024, 256, 0, stream>>>(x, Wt, Qs, Ks, Vt);

    if (ws_size >= (25u << 20)) {
        attn<4><<<2048, 64, 0, stream>>>(Qs, Ks, Vt, out, accP, mP, lP);
        combine<4><<<4096, 256, 0, stream>>>(accP, mP, lP, out);
    } else {
        attn<1><<<512, 64, 0, stream>>>(Qs, Ks, Vt, out, accP, mP, lP);
    }
}

// Round 23
// 69.581 us; speedup vs baseline: 1.0114x; 1.0026x over previous
//
#include <hip/hip_runtime.h>
#include <hip/hip_bf16.h>

typedef __attribute__((ext_vector_type(8))) short short8;
typedef __attribute__((ext_vector_type(4))) float f32x4;

#define MFMA16(a, b, c) __builtin_amdgcn_mfma_f32_16x16x32_bf16((a), (b), (c), 0, 0, 0)

// scalar round-to-nearest-even f32 -> bf16 bits (proven rounds 1/3/6)
__device__ inline unsigned short f2bf(float f) {
    union { float f; unsigned int u; } v;
    v.f = f;
    unsigned int u = v.u;
    return (unsigned short)((u + 0x7fffu + ((u >> 16) & 1u)) >> 16);
}

__device__ inline float bf2f(unsigned short u) {
    union { unsigned int u; float f; } v;
    v.u = ((unsigned int)u) << 16;
    return v.f;
}

// ---------------------------------------------------------------------------
// FRAGMENT-ORDER LAYOUTS (proven round 18): for each (16-row tile, 32-col
// chunk) the 64 lanes' 16B fragments are stored contiguously -> one wave
// MFMA-operand load = ONE contiguous 1KB block.
// ---------------------------------------------------------------------------
__device__ inline size_t WF(int n, int c) {
    return ((((size_t)(n >> 4)) * 32 + (c >> 5)) * 64 + ((c >> 3) & 3) * 16 + (n & 15)) * 8 + (c & 7);
}
__device__ inline size_t QKF(int q, int h) {
    return ((((size_t)(q >> 4)) * 2 + (h >> 5)) * 64 + ((h >> 3) & 3) * 16 + (q & 15)) * 8 + (h & 7);
}
__device__ inline size_t VF(int h, int t) {
    return ((((size_t)(h >> 4)) * 128 + (t >> 5)) * 64 + ((t >> 3) & 3) * 16 + (h & 15)) * 8 + (t & 7);
}

// ---------------------------------------------------------------------------
// prep_w: Wt in fragment order. n in [0,192): 0..63 Wq (pre-scaled 1/8),
// 64..127 Wk, 128..191 Wv
// ---------------------------------------------------------------------------
__global__ __launch_bounds__(256) void prep_w(const float* __restrict__ Wq,
                                              const float* __restrict__ Wk,
                                              const float* __restrict__ Wv,
                                              unsigned short* __restrict__ Wt) {
    int idx = blockIdx.x * 256 + threadIdx.x;
    if (idx >= 192 * 1024) return;
    int n = idx >> 10;
    int c = idx & 1023;
    const float* W = (n < 64) ? Wq : ((n < 128) ? Wk : Wv);
    float v = W[c * 64 + (n & 63)];
    if (n < 64) v *= 0.125f;  // fold 1/sqrt(head_size) into Wq
    Wt[WF(n, c)] = f2bf(v);
}

// ---------------------------------------------------------------------------
// projt: WHOLE-TILE REG-STAGED projection. 1024 blocks x 4 waves, 2 blocks/CU.
// Staging = plain uint4 register loads (the 6-TB/s-proven path; 1KB/wave
// contiguous bursts, 8KB in flight per wave) + ds_write_b128 into the SAME
// swizzled layout as r21 (write chunk l = (g&~15)|((g&15)^row), involution
// of the read). One barrier; compute phase byte-identical to r21.
// ---------------------------------------------------------------------------
__global__ __launch_bounds__(256, 2) void projt(const float* __restrict__ x,
                                                const unsigned short* __restrict__ Wt,
                                                unsigned short* __restrict__ Qs,
                                                unsigned short* __restrict__ Ks,
                                                unsigned short* __restrict__ Vt) {
    __shared__ __align__(16) float xbuf[16 * 1024];  // 64 KB whole tile

    const int tid = threadIdx.x;
    const int w = tid >> 6;
    const int lane = tid & 63;
    const int lr = lane & 15;
    const int lg = lane >> 4;
    const int t0 = blockIdx.x * 16;

    // ---- reg-stage whole x row-tile: wave w stages rows [w*4, w*4+4) ----
    // Each row = 256 uint4 chunks; lane loads chunk seg*64+lane (1KB/wave
    // contiguous). Two rounds of {8 loads -> 8 swizzled ds_writes}.
    {
        const uint4* xr = (const uint4*)(x + (size_t)t0 * 1024);
#pragma unroll
        for (int half = 0; half < 2; half++) {
            uint4 v[8];
#pragma unroll
            for (int rr = 0; rr < 2; rr++)
#pragma unroll
                for (int seg = 0; seg < 4; seg++)
                    v[rr * 4 + seg] =
                        xr[(size_t)(w * 4 + half * 2 + rr) * 256 + seg * 64 + lane];
#pragma unroll
            for (int rr = 0; rr < 2; rr++)
#pragma unroll
                for (int seg = 0; seg < 4; seg++) {
                    int row = w * 4 + half * 2 + rr;
                    int g = seg * 64 + lane;                   // global chunk
                    int l = (g & ~15) | ((g & 15) ^ row);      // swizzled LDS chunk
                    *(uint4*)&xbuf[row * 1024 + l * 4] = v[rr * 4 + seg];
                }
        }
    }
    __syncthreads();  // single drain; compute below is barrier-free

    f32x4 acc[3];
#pragma unroll
    for (int i = 0; i < 3; i++) acc[i] = (f32x4){0.f, 0.f, 0.f, 0.f};

    for (int t = 0; t < 8; ++t) {
        const int ch0 = t * 32;  // 16B-chunk base

        // batch this step's 12 fragment-order W loads (contiguous 1KB each)
        short8 bfr[4][3];
#pragma unroll
        for (int h = 0; h < 4; h++)
#pragma unroll
            for (int nt = 0; nt < 3; nt++)
                bfr[h][nt] = *(const short8*)(Wt +
                    (((size_t)(w * 3 + nt) * 32 + (t * 4 + h)) * 64 + lane) * 8);

#pragma unroll
        for (int h = 0; h < 4; h++) {
            int cb = ch0 + h * 8 + lg * 2;
            int l0 = (cb & ~15) | ((cb & 15) ^ lr);
            int l1 = ((cb + 1) & ~15) | (((cb + 1) & 15) ^ lr);
            float4 a0 = *(const float4*)&xbuf[lr * 1024 + l0 * 4];
            float4 a1 = *(const float4*)&xbuf[lr * 1024 + l1 * 4];
            short8 a;
            a[0] = (short)f2bf(a0.x); a[1] = (short)f2bf(a0.y);
            a[2] = (short)f2bf(a0.z); a[3] = (short)f2bf(a0.w);
            a[4] = (short)f2bf(a1.x); a[5] = (short)f2bf(a1.y);
            a[6] = (short)f2bf(a1.z); a[7] = (short)f2bf(a1.w);
#pragma unroll
            for (int nt = 0; nt < 3; nt++) acc[nt] = MFMA16(a, bfr[h][nt], acc[nt]);
        }
    }

    // epilogue: D col = lr -> n, row = lg*4+r -> t; fragment-order writes
    const int nbase = w * 48;
#pragma unroll
    for (int nt = 0; nt < 3; nt++) {
#pragma unroll
        for (int r = 0; r < 4; r++) {
            int n = nbase + nt * 16 + lr;
            int tq = t0 + lg * 4 + r;
            int b = tq >> 12;
            int qq = tq & 4095;
            unsigned short val = f2bf(acc[nt][r]);
            if (n < 64) {
                Qs[(size_t)b * 262144 + QKF(qq, n)] = val;
            } else if (n < 128) {
                Ks[(size_t)b * 262144 + QKF(qq, n - 64)] = val;
            } else {
                Vt[(size_t)b * 262144 + VF(n - 128, qq)] = val;
            }
        }
    }
}

// ---------------------------------------------------------------------------
// attn<NS>: causal flash attention, swapped QK^T (S^T = K*Q), QBLK=32,
// KVBLK=64, 1 wave/block, KV split into NS chunks. Barrier-free inner loop
// (single-wave blocks; lgkmcnt fence only). All Q/K/V loads are contiguous
// 1KB fragment-order wave-loads. (Identical to rounds 18-22.)
// ---------------------------------------------------------------------------
#define SROW 72  // P-tile row stride in halfwords (144 B/row)

template <int NS>
__global__ __launch_bounds__(64) void attn(const unsigned short* __restrict__ Qs,
                                           const unsigned short* __restrict__ Ks,
                                           const unsigned short* __restrict__ Vt,
                                           float* __restrict__ out,
                                           unsigned short* __restrict__ accP,
                                           float* __restrict__ mP,
                                           float* __restrict__ lP) {
    __shared__ unsigned short pl[32 * SROW];  // 32 q-rows x 64 kv-cols

    const int ntasks = 512 * NS;
    int raw = ntasks - 1 - blockIdx.x;  // longest scans first
    int qt_g = raw / NS;
    int c = raw - qt_g * NS;
    int qt = qt_g >> 2;
    int b = qt_g & 3;
    int q0 = qt * 32;

    int lane = threadIdx.x;
    int lr = lane & 15;
    int lg = lane >> 4;

    const unsigned short* Qb = Qs + (size_t)b * 262144;
    const unsigned short* Kb = Ks + (size_t)b * 262144;
    const unsigned short* Vb = Vt + (size_t)b * 262144;

    short8 qf[2][2];
#pragma unroll
    for (int qs = 0; qs < 2; qs++)
#pragma unroll
        for (int kh = 0; kh < 2; kh++)
            qf[qs][kh] = *(const short8*)(Qb +
                (((size_t)((q0 >> 4) + qs) * 2 + kh) * 64 + lane) * 8);

    f32x4 acc[4][2];  // [ht][qs]
#pragma unroll
    for (int i = 0; i < 4; i++)
#pragma unroll
        for (int qs = 0; qs < 2; qs++) acc[i][qs] = (f32x4){0.f, 0.f, 0.f, 0.f};
    float m[2] = {-1e30f, -1e30f};
    float l[2] = {0.f, 0.f};  // LANE-PARTIAL

    int nt = (q0 + 95) >> 6;  // ceil((q0+32)/64)
    int tb = (c * nt) / NS;
    int te = ((c + 1) * nt) / NS;

    // ---- preload K fragments for first tile ----
    short8 kf[4][2];
    if (tb < te) {
#pragma unroll
        for (int t = 0; t < 4; t++)
#pragma unroll
            for (int half = 0; half < 2; half++)
                kf[t][half] = *(const short8*)(Kb +
                    (((size_t)((tb * 64) >> 4) + t) * 2 + half) * 512 + lane * 8);
    }

    for (int t64 = tb; t64 < te; ++t64) {
        int kv0 = t64 * 64;

        // ---- S^T = K Q (consumes kf) ----
        f32x4 s[4][2];
#pragma unroll
        for (int t = 0; t < 4; t++)
#pragma unroll
            for (int qs = 0; qs < 2; qs++) {
                f32x4 z = (f32x4){0.f, 0.f, 0.f, 0.f};
                z = MFMA16(kf[t][0], qf[qs][0], z);
                z = MFMA16(kf[t][1], qf[qs][1], z);
                s[t][qs] = z;
            }

        // ---- issue V loads (contiguous 1KB each; in flight thru softmax) ----
        short8 vf[4][2];
#pragma unroll
        for (int ht = 0; ht < 4; ht++)
#pragma unroll
            for (int half = 0; half < 2; half++)
                vf[ht][half] = *(const short8*)(Vb +
                    (((size_t)ht * 128 + (kv0 >> 5) + half) * 64 + lane) * 8);

        // ---- reload kf for NEXT tile (latency hides under softmax+PV) ----
        if (t64 + 1 < te) {
            int kvn = (t64 + 1) * 64;
#pragma unroll
            for (int t = 0; t < 4; t++)
#pragma unroll
                for (int half = 0; half < 2; half++)
                    kf[t][half] = *(const short8*)(Kb +
                        (((size_t)(kvn >> 4) + t) * 2 + half) * 512 + lane * 8);
        }

        // ---- causal mask (only the straddling tile needs it) ----
        if (kv0 + 63 > q0) {
#pragma unroll
            for (int t = 0; t < 4; t++)
#pragma unroll
                for (int qs = 0; qs < 2; qs++)
#pragma unroll
                    for (int r = 0; r < 4; r++) {
                        int kv = kv0 + t * 16 + lg * 4 + r;
                        if (kv > q0 + qs * 16 + lr) s[t][qs][r] = -1e30f;
                    }
        }

        // ---- lane-local tile max (for defer-max check) ----
        float pmax[2] = {-1e30f, -1e30f};
#pragma unroll
        for (int t = 0; t < 4; t++)
#pragma unroll
            for (int qs = 0; qs < 2; qs++)
#pragma unroll
                for (int r = 0; r < 4; r++) pmax[qs] = fmaxf(pmax[qs], s[t][qs][r]);

        int ok = (pmax[0] <= m[0] + 8.0f) && (pmax[1] <= m[1] + 8.0f);
        if (!__all(ok)) {
            float alpha[2];
#pragma unroll
            for (int qs = 0; qs < 2; qs++) {
                float mx = pmax[qs];
                mx = fmaxf(mx, __shfl_xor(mx, 16));
                mx = fmaxf(mx, __shfl_xor(mx, 32));
                float mn = fmaxf(m[qs], mx);
                alpha[qs] = __expf(m[qs] - mn);
                m[qs] = mn;
                l[qs] *= alpha[qs];
            }
            float ar[2][4];
#pragma unroll
            for (int qs = 0; qs < 2; qs++)
#pragma unroll
                for (int r = 0; r < 4; r++) ar[qs][r] = __shfl(alpha[qs], lg * 4 + r);
#pragma unroll
            for (int ht = 0; ht < 4; ht++)
#pragma unroll
                for (int qs = 0; qs < 2; qs++)
#pragma unroll
                    for (int r = 0; r < 4; r++) acc[ht][qs][r] *= ar[qs][r];
        }

        // ---- exp + lane-partial l accumulation ----
#pragma unroll
        for (int t = 0; t < 4; t++)
#pragma unroll
            for (int qs = 0; qs < 2; qs++)
#pragma unroll
                for (int r = 0; r < 4; r++) {
                    float e = __expf(s[t][qs][r] - m[qs]);
                    s[t][qs][r] = e;
                    l[qs] += e;
                }

        // ---- pack P -> LDS (single-wave: lgkmcnt fence only, rule #18) ----
#pragma unroll
        for (int qs = 0; qs < 2; qs++)
#pragma unroll
            for (int t = 0; t < 4; t++) {
                uint2 uu;
                uu.x = (unsigned)f2bf(s[t][qs][0]) | ((unsigned)f2bf(s[t][qs][1]) << 16);
                uu.y = (unsigned)f2bf(s[t][qs][2]) | ((unsigned)f2bf(s[t][qs][3]) << 16);
                *(uint2*)&pl[(qs * 16 + lr) * SROW + t * 16 + lg * 4] = uu;
            }
        asm volatile("s_waitcnt lgkmcnt(0)" ::: "memory");
        __builtin_amdgcn_sched_barrier(0);
        short8 pa[2][2];
#pragma unroll
        for (int qs = 0; qs < 2; qs++)
#pragma unroll
            for (int half = 0; half < 2; half++)
                pa[qs][half] = *(const short8*)&pl[(qs * 16 + lr) * SROW +
                                                   half * 32 + lg * 8];

        // ---- O += P V ----
#pragma unroll
        for (int ht = 0; ht < 4; ht++)
#pragma unroll
            for (int qs = 0; qs < 2; qs++) {
                acc[ht][qs] = MFMA16(pa[qs][0], vf[ht][0], acc[ht][qs]);
                acc[ht][qs] = MFMA16(pa[qs][1], vf[ht][1], acc[ht][qs]);
            }
    }

    // ---- epilogue: reduce lane-partial l across the 4 lg groups ----
    float lt[2];
#pragma unroll
    for (int qs = 0; qs < 2; qs++) {
        float v = l[qs];
        v += __shfl_xor(v, 16);
        v += __shfl_xor(v, 32);
        lt[qs] = v;
    }

    if (NS == 1) {
        float rl[2][4];
#pragma unroll
        for (int qs = 0; qs < 2; qs++)
#pragma unroll
            for (int r = 0; r < 4; r++) rl[qs][r] = 1.0f / __shfl(lt[qs], lg * 4 + r);
#pragma unroll
        for (int ht = 0; ht < 4; ht++)
#pragma unroll
            for (int qs = 0; qs < 2; qs++)
#pragma unroll
                for (int r = 0; r < 4; r++) {
                    size_t o = ((size_t)b * 4096 + q0 + qs * 16 + lg * 4 + r) * 64 +
                               ht * 16 + lr;
                    out[o] = acc[ht][qs][r] * rl[qs][r];
                }
    } else {
        int tidx = qt_g * NS + c;
        unsigned short* ap = accP + (size_t)tidx * 2048;
#pragma unroll
        for (int ht = 0; ht < 4; ht++)
#pragma unroll
            for (int qs = 0; qs < 2; qs++)
#pragma unroll
                for (int r = 0; r < 4; r++)
                    ap[(qs * 16 + lg * 4 + r) * 64 + ht * 16 + lr] =
                        f2bf(acc[ht][qs][r]);
        if (lane < 16) {
#pragma unroll
            for (int qs = 0; qs < 2; qs++) {
                mP[tidx * 32 + qs * 16 + lane] = m[qs];
                lP[tidx * 32 + qs * 16 + lane] = lt[qs];
            }
        }
    }
}

// ---------------------------------------------------------------------------
// combine<NS>: out[row][h] = sum_c e^{m_c-M} acc_c / sum_c e^{m_c-M} l_c
// (bf16 partials)
// ---------------------------------------------------------------------------
template <int NS>
__global__ __launch_bounds__(256) void combine(const unsigned short* __restrict__ accP,
                                               const float* __restrict__ mP,
                                               const float* __restrict__ lP,
                                               float* __restrict__ out) {
    int g = blockIdx.x * 256 + threadIdx.x;  // 0 .. 1M-1
    int h = g & 63;
    int row = g >> 6;       // b*4096 + t
    int b = row >> 12;
    int t = row & 4095;
    int qt = t >> 5;
    int qr = t & 31;
    int qt_g = qt * 4 + b;

    float mc[NS];
    float M = -1e30f;
#pragma unroll
    for (int c = 0; c < NS; c++) {
        mc[c] = mP[(qt_g * NS + c) * 32 + qr];
        M = fmaxf(M, mc[c]);
    }
    float num = 0.f, den = 0.f;
#pragma unroll
    for (int c = 0; c < NS; c++) {
        float wgt = __expf(mc[c] - M);
        den += wgt * lP[(qt_g * NS + c) * 32 + qr];
        num += wgt * bf2f(accP[(size_t)(qt_g * NS + c) * 2048 + qr * 64 + h]);
    }
    out[g] = num / den;
}

// ---------------------------------------------------------------------------
extern "C" void kernel_launch(void* const* d_in, const int* in_sizes, int n_in,
                              void* d_out, int out_size, void* d_ws, size_t ws_size,
                              hipStream_t stream) {
    const float* x  = (const float*)d_in[0];
    const float* Wq = (const float*)d_in[1];
    const float* Wk = (const float*)d_in[2];
    const float* Wv = (const float*)d_in[3];
    float* out = (float*)d_out;

    char* ws = (char*)d_ws;
    unsigned short* Qs = (unsigned short*)(ws);                   // 2 MB @ 0
    unsigned short* Ks = (unsigned short*)(ws + (2u << 20));      // 2 MB @ 2M
    unsigned short* Vt = (unsigned short*)(ws + (4u << 20));      // 2 MB @ 4M
    unsigned short* Wt = (unsigned short*)(ws + (6u << 20));      // 384 KB @ 6M
    unsigned short* accP = (unsigned short*)(ws + (8u << 20));    // 8 MB @ 8M (2048 tasks x 4KB bf16)
    float* mP = (float*)(ws + (24u << 20));                       // 256 KB @ 24M
    float* lP = (float*)(ws + (24u << 20) + (512u << 10));        // 256 KB

    prep_w<<<768, 256, 0, stream>>>(Wq, Wk, Wv, Wt);
    projt<<<1024, 256, 0, stream>>>(x, Wt, Qs, Ks, Vt);

    if (ws_size >= (25u << 20)) {
        attn<4><<<2048, 64, 0, stream>>>(Qs, Ks, Vt, out, accP, mP, lP);
        combine<4><<<4096, 256, 0, stream>>>(accP, mP, lP, out);
    } else {
        attn<1><<<512, 64, 0, stream>>>(Qs, Ks, Vt, out, accP, mP, lP);
    }
}

// Round 24
// 64.195 us; speedup vs baseline: 1.0962x; 1.0839x over previous
//
#include <hip/hip_runtime.h>
#include <hip/hip_bf16.h>

typedef __attribute__((ext_vector_type(8))) short short8;
typedef __attribute__((ext_vector_type(4))) float f32x4;

#define MFMA16(a, b, c) __builtin_amdgcn_mfma_f32_16x16x32_bf16((a), (b), (c), 0, 0, 0)

// scalar round-to-nearest-even f32 -> bf16 bits (proven rounds 1/3/6)
__device__ inline unsigned short f2bf(float f) {
    union { float f; unsigned int u; } v;
    v.f = f;
    unsigned int u = v.u;
    return (unsigned short)((u + 0x7fffu + ((u >> 16) & 1u)) >> 16);
}

__device__ inline float bf2f(unsigned short u) {
    union { unsigned int u; float f; } v;
    v.u = ((unsigned int)u) << 16;
    return v.f;
}

// ---------------------------------------------------------------------------
// FRAGMENT-ORDER LAYOUTS (proven round 18).
// ---------------------------------------------------------------------------
__device__ inline size_t WF(int n, int c) {
    return ((((size_t)(n >> 4)) * 32 + (c >> 5)) * 64 + ((c >> 3) & 3) * 16 + (n & 15)) * 8 + (c & 7);
}
__device__ inline size_t QKF(int q, int h) {
    return ((((size_t)(q >> 4)) * 2 + (h >> 5)) * 64 + ((h >> 3) & 3) * 16 + (q & 15)) * 8 + (h & 7);
}
__device__ inline size_t VF(int h, int t) {
    return ((((size_t)(h >> 4)) * 128 + (t >> 5)) * 64 + ((t >> 3) & 3) * 16 + (h & 15)) * 8 + (t & 7);
}

// ---------------------------------------------------------------------------
// prep_w: Wt in fragment order. n in [0,192): 0..63 Wq (pre-scaled 1/8),
// 64..127 Wk, 128..191 Wv
// ---------------------------------------------------------------------------
__global__ __launch_bounds__(256) void prep_w(const float* __restrict__ Wq,
                                              const float* __restrict__ Wk,
                                              const float* __restrict__ Wv,
                                              unsigned short* __restrict__ Wt) {
    int idx = blockIdx.x * 256 + threadIdx.x;
    if (idx >= 192 * 1024) return;
    int n = idx >> 10;
    int c = idx & 1023;
    const float* W = (n < 64) ? Wq : ((n < 128) ? Wk : Wv);
    float v = W[c * 64 + (n & 63)];
    if (n < 64) v *= 0.125f;  // fold 1/sqrt(head_size) into Wq
    Wt[WF(n, c)] = f2bf(v);
}

// ---------------------------------------------------------------------------
// projt: REG-STAGED SLAB PIPELINE. 1024 blocks x 4 waves, 4 blocks/CU
// (LDS 16 KB ring). Slab = 16 rows x 128 cols f32 (8 KB). Slab t+2 lives in
// registers (2 uint4/wave) while slab t computes; raw s_barrier + lgkm-only
// fence per step -> global loads NEVER drained by a barrier; x streams
// continuously under compute. Ring parity: write slab t+1 into
// ring[(t+1)&1], last read at step t-1, protected by this step's barrier.
// Swizzle within 16-chunk windows (chunk -> chunk^row), both sides.
// ---------------------------------------------------------------------------
__global__ __launch_bounds__(256, 4) void projt(const float* __restrict__ x,
                                                const unsigned short* __restrict__ Wt,
                                                unsigned short* __restrict__ Qs,
                                                unsigned short* __restrict__ Ks,
                                                unsigned short* __restrict__ Vt) {
    __shared__ __align__(16) float xbuf[2][16 * 128];  // ring of 2 slabs, 16 KB

    const int tid = threadIdx.x;
    const int w = tid >> 6;
    const int lane = tid & 63;
    const int lr = lane & 15;
    const int lg = lane >> 4;
    const int t0 = blockIdx.x * 16;

    // wave w owns slab rows [w*4, w*4+4); lane l covers row w*4+j*2+(l>>5),
    // chunk (l&31) of 32 16B-chunks per row (512 B/row).
    const int srow0 = w * 4 + (lane >> 5);  // +j*2
    const int schunk = lane & 31;

#define LOADSLAB(v, sl)                                                         \
    {                                                                           \
        const uint4* xr = (const uint4*)(x + (size_t)(t0) * 1024 + (sl) * 128); \
        v[0] = xr[(size_t)(srow0) * 256 + schunk];                              \
        v[1] = xr[(size_t)(srow0 + 2) * 256 + schunk];                          \
    }

#define DSWRITE(buf, v)                                                         \
    {                                                                           \
        _Pragma("unroll")                                                       \
        for (int j = 0; j < 2; j++) {                                           \
            int row = srow0 + j * 2;                                            \
            int l = (schunk & ~15) | ((schunk & 15) ^ (row & 15));              \
            *(uint4*)&xbuf[buf][row * 128 + l * 4] = v[j];                      \
        }                                                                       \
    }

    // prologue: slab0 -> ring[0]; slab1 -> regs
    uint4 vc[2], vn[2];
    LOADSLAB(vc, 0);
    DSWRITE(0, vc);               // compiler waits vmcnt for vc before ds_write
    LOADSLAB(vc, 1);

    f32x4 acc[3];
#pragma unroll
    for (int i = 0; i < 3; i++) acc[i] = (f32x4){0.f, 0.f, 0.f, 0.f};

#pragma unroll
    for (int t = 0; t < 8; ++t) {
        if (t + 2 < 8) LOADSLAB(vn, t + 2);

        asm volatile("s_waitcnt lgkmcnt(0)" ::: "memory");
        __builtin_amdgcn_sched_barrier(0);
        __builtin_amdgcn_s_barrier();   // all waves done reading ring[(t+1)&1]
        __builtin_amdgcn_sched_barrier(0);

        if (t + 1 < 8) DSWRITE((t + 1) & 1, vc);  // publish slab t+1

        // ---- compute slab t from ring[t&1] ----
        const float* xb = &xbuf[t & 1][0];
#pragma unroll
        for (int h = 0; h < 4; h++) {
            short8 bfr[3];
#pragma unroll
            for (int nt = 0; nt < 3; nt++)
                bfr[nt] = *(const short8*)(Wt +
                    (((size_t)(w * 3 + nt) * 32 + (t * 4 + h)) * 64 + lane) * 8);
            int cb = h * 8 + lg * 2;  // within-slab 16B-chunk (0..31)
            int l0 = (cb & ~15) | ((cb & 15) ^ lr);
            int l1 = ((cb + 1) & ~15) | (((cb + 1) & 15) ^ lr);
            float4 a0 = *(const float4*)&xb[lr * 128 + l0 * 4];
            float4 a1 = *(const float4*)&xb[lr * 128 + l1 * 4];
            short8 a;
            a[0] = (short)f2bf(a0.x); a[1] = (short)f2bf(a0.y);
            a[2] = (short)f2bf(a0.z); a[3] = (short)f2bf(a0.w);
            a[4] = (short)f2bf(a1.x); a[5] = (short)f2bf(a1.y);
            a[6] = (short)f2bf(a1.z); a[7] = (short)f2bf(a1.w);
#pragma unroll
            for (int nt = 0; nt < 3; nt++) acc[nt] = MFMA16(a, bfr[nt], acc[nt]);
        }

        if (t + 2 < 8) { vc[0] = vn[0]; vc[1] = vn[1]; }  // guarded rotate (no UB)
    }

    // epilogue: D col = lr -> n, row = lg*4+r -> t; fragment-order writes
    const int nbase = w * 48;
#pragma unroll
    for (int nt = 0; nt < 3; nt++) {
#pragma unroll
        for (int r = 0; r < 4; r++) {
            int n = nbase + nt * 16 + lr;
            int tq = t0 + lg * 4 + r;
            int b = tq >> 12;
            int qq = tq & 4095;
            unsigned short val = f2bf(acc[nt][r]);
            if (n < 64) {
                Qs[(size_t)b * 262144 + QKF(qq, n)] = val;
            } else if (n < 128) {
                Ks[(size_t)b * 262144 + QKF(qq, n - 64)] = val;
            } else {
                Vt[(size_t)b * 262144 + VF(n - 128, qq)] = val;
            }
        }
    }
}

// ---------------------------------------------------------------------------
// attn<NS>: causal flash attention, swapped QK^T (S^T = K*Q), QBLK=32,
// KVBLK=64, 1 wave/block, KV split into NS chunks. Barrier-free inner loop
// (single-wave blocks; lgkmcnt fence only). All Q/K/V loads are contiguous
// 1KB fragment-order wave-loads. (Identical to rounds 18-23.)
// ---------------------------------------------------------------------------
#define SROW 72  // P-tile row stride in halfwords (144 B/row)

template <int NS>
__global__ __launch_bounds__(64) void attn(const unsigned short* __restrict__ Qs,
                                           const unsigned short* __restrict__ Ks,
                                           const unsigned short* __restrict__ Vt,
                                           float* __restrict__ out,
                                           unsigned short* __restrict__ accP,
                                           float* __restrict__ mP,
                                           float* __restrict__ lP) {
    __shared__ unsigned short pl[32 * SROW];  // 32 q-rows x 64 kv-cols

    const int ntasks = 512 * NS;
    int raw = ntasks - 1 - blockIdx.x;  // longest scans first
    int qt_g = raw / NS;
    int c = raw - qt_g * NS;
    int qt = qt_g >> 2;
    int b = qt_g & 3;
    int q0 = qt * 32;

    int lane = threadIdx.x;
    int lr = lane & 15;
    int lg = lane >> 4;

    const unsigned short* Qb = Qs + (size_t)b * 262144;
    const unsigned short* Kb = Ks + (size_t)b * 262144;
    const unsigned short* Vb = Vt + (size_t)b * 262144;

    short8 qf[2][2];
#pragma unroll
    for (int qs = 0; qs < 2; qs++)
#pragma unroll
        for (int kh = 0; kh < 2; kh++)
            qf[qs][kh] = *(const short8*)(Qb +
                (((size_t)((q0 >> 4) + qs) * 2 + kh) * 64 + lane) * 8);

    f32x4 acc[4][2];  // [ht][qs]
#pragma unroll
    for (int i = 0; i < 4; i++)
#pragma unroll
        for (int qs = 0; qs < 2; qs++) acc[i][qs] = (f32x4){0.f, 0.f, 0.f, 0.f};
    float m[2] = {-1e30f, -1e30f};
    float l[2] = {0.f, 0.f};  // LANE-PARTIAL

    int nt = (q0 + 95) >> 6;  // ceil((q0+32)/64)
    int tb = (c * nt) / NS;
    int te = ((c + 1) * nt) / NS;

    // ---- preload K fragments for first tile ----
    short8 kf[4][2];
    if (tb < te) {
#pragma unroll
        for (int t = 0; t < 4; t++)
#pragma unroll
            for (int half = 0; half < 2; half++)
                kf[t][half] = *(const short8*)(Kb +
                    (((size_t)((tb * 64) >> 4) + t) * 2 + half) * 512 + lane * 8);
    }

    for (int t64 = tb; t64 < te; ++t64) {
        int kv0 = t64 * 64;

        // ---- S^T = K Q (consumes kf) ----
        f32x4 s[4][2];
#pragma unroll
        for (int t = 0; t < 4; t++)
#pragma unroll
            for (int qs = 0; qs < 2; qs++) {
                f32x4 z = (f32x4){0.f, 0.f, 0.f, 0.f};
                z = MFMA16(kf[t][0], qf[qs][0], z);
                z = MFMA16(kf[t][1], qf[qs][1], z);
                s[t][qs] = z;
            }

        // ---- issue V loads (contiguous 1KB each; in flight thru softmax) ----
        short8 vf[4][2];
#pragma unroll
        for (int ht = 0; ht < 4; ht++)
#pragma unroll
            for (int half = 0; half < 2; half++)
                vf[ht][half] = *(const short8*)(Vb +
                    (((size_t)ht * 128 + (kv0 >> 5) + half) * 64 + lane) * 8);

        // ---- reload kf for NEXT tile (latency hides under softmax+PV) ----
        if (t64 + 1 < te) {
            int kvn = (t64 + 1) * 64;
#pragma unroll
            for (int t = 0; t < 4; t++)
#pragma unroll
                for (int half = 0; half < 2; half++)
                    kf[t][half] = *(const short8*)(Kb +
                        (((size_t)(kvn >> 4) + t) * 2 + half) * 512 + lane * 8);
        }

        // ---- causal mask (only the straddling tile needs it) ----
        if (kv0 + 63 > q0) {
#pragma unroll
            for (int t = 0; t < 4; t++)
#pragma unroll
                for (int qs = 0; qs < 2; qs++)
#pragma unroll
                    for (int r = 0; r < 4; r++) {
                        int kv = kv0 + t * 16 + lg * 4 + r;
                        if (kv > q0 + qs * 16 + lr) s[t][qs][r] = -1e30f;
                    }
        }

        // ---- lane-local tile max (for defer-max check) ----
        float pmax[2] = {-1e30f, -1e30f};
#pragma unroll
        for (int t = 0; t < 4; t++)
#pragma unroll
            for (int qs = 0; qs < 2; qs++)
#pragma unroll
                for (int r = 0; r < 4; r++) pmax[qs] = fmaxf(pmax[qs], s[t][qs][r]);

        int ok = (pmax[0] <= m[0] + 8.0f) && (pmax[1] <= m[1] + 8.0f);
        if (!__all(ok)) {
            float alpha[2];
#pragma unroll
            for (int qs = 0; qs < 2; qs++) {
                float mx = pmax[qs];
                mx = fmaxf(mx, __shfl_xor(mx, 16));
                mx = fmaxf(mx, __shfl_xor(mx, 32));
                float mn = fmaxf(m[qs], mx);
                alpha[qs] = __expf(m[qs] - mn);
                m[qs] = mn;
                l[qs] *= alpha[qs];
            }
            float ar[2][4];
#pragma unroll
            for (int qs = 0; qs < 2; qs++)
#pragma unroll
                for (int r = 0; r < 4; r++) ar[qs][r] = __shfl(alpha[qs], lg * 4 + r);
#pragma unroll
            for (int ht = 0; ht < 4; ht++)
#pragma unroll
                for (int qs = 0; qs < 2; qs++)
#pragma unroll
                    for (int r = 0; r < 4; r++) acc[ht][qs][r] *= ar[qs][r];
        }

        // ---- exp + lane-partial l accumulation ----
#pragma unroll
        for (int t = 0; t < 4; t++)
#pragma unroll
            for (int qs = 0; qs < 2; qs++)
#pragma unroll
                for (int r = 0; r < 4; r++) {
                    float e = __expf(s[t][qs][r] - m[qs]);
                    s[t][qs][r] = e;
                    l[qs] += e;
                }

        // ---- pack P -> LDS (single-wave: lgkmcnt fence only, rule #18) ----
#pragma unroll
        for (int qs = 0; qs < 2; qs++)
#pragma unroll
            for (int t = 0; t < 4; t++) {
                uint2 uu;
                uu.x = (unsigned)f2bf(s[t][qs][0]) | ((unsigned)f2bf(s[t][qs][1]) << 16);
                uu.y = (unsigned)f2bf(s[t][qs][2]) | ((unsigned)f2bf(s[t][qs][3]) << 16);
                *(uint2*)&pl[(qs * 16 + lr) * SROW + t * 16 + lg * 4] = uu;
            }
        asm volatile("s_waitcnt lgkmcnt(0)" ::: "memory");
        __builtin_amdgcn_sched_barrier(0);
        short8 pa[2][2];
#pragma unroll
        for (int qs = 0; qs < 2; qs++)
#pragma unroll
            for (int half = 0; half < 2; half++)
                pa[qs][half] = *(const short8*)&pl[(qs * 16 + lr) * SROW +
                                                   half * 32 + lg * 8];

        // ---- O += P V ----
#pragma unroll
        for (int ht = 0; ht < 4; ht++)
#pragma unroll
            for (int qs = 0; qs < 2; qs++) {
                acc[ht][qs] = MFMA16(pa[qs][0], vf[ht][0], acc[ht][qs]);
                acc[ht][qs] = MFMA16(pa[qs][1], vf[ht][1], acc[ht][qs]);
            }
    }

    // ---- epilogue: reduce lane-partial l across the 4 lg groups ----
    float lt[2];
#pragma unroll
    for (int qs = 0; qs < 2; qs++) {
        float v = l[qs];
        v += __shfl_xor(v, 16);
        v += __shfl_xor(v, 32);
        lt[qs] = v;
    }

    if (NS == 1) {
        float rl[2][4];
#pragma unroll
        for (int qs = 0; qs < 2; qs++)
#pragma unroll
            for (int r = 0; r < 4; r++) rl[qs][r] = 1.0f / __shfl(lt[qs], lg * 4 + r);
#pragma unroll
        for (int ht = 0; ht < 4; ht++)
#pragma unroll
            for (int qs = 0; qs < 2; qs++)
#pragma unroll
                for (int r = 0; r < 4; r++) {
                    size_t o = ((size_t)b * 4096 + q0 + qs * 16 + lg * 4 + r) * 64 +
                               ht * 16 + lr;
                    out[o] = acc[ht][qs][r] * rl[qs][r];
                }
    } else {
        int tidx = qt_g * NS + c;
        unsigned short* ap = accP + (size_t)tidx * 2048;
#pragma unroll
        for (int ht = 0; ht < 4; ht++)
#pragma unroll
            for (int qs = 0; qs < 2; qs++)
#pragma unroll
                for (int r = 0; r < 4; r++)
                    ap[(qs * 16 + lg * 4 + r) * 64 + ht * 16 + lr] =
                        f2bf(acc[ht][qs][r]);
        if (lane < 16) {
#pragma unroll
            for (int qs = 0; qs < 2; qs++) {
                mP[tidx * 32 + qs * 16 + lane] = m[qs];
                lP[tidx * 32 + qs * 16 + lane] = lt[qs];
            }
        }
    }
}

// ---------------------------------------------------------------------------
// combine<NS>: out[row][h] = sum_c e^{m_c-M} acc_c / sum_c e^{m_c-M} l_c
// (bf16 partials)
// ---------------------------------------------------------------------------
template <int NS>
__global__ __launch_bounds__(256) void combine(const unsigned short* __restrict__ accP,
                                               const float* __restrict__ mP,
                                               const float* __restrict__ lP,
                                               float* __restrict__ out) {
    int g = blockIdx.x * 256 + threadIdx.x;  // 0 .. 1M-1
    int h = g & 63;
    int row = g >> 6;       // b*4096 + t
    int b = row >> 12;
    int t = row & 4095;
    int qt = t >> 5;
    int qr = t & 31;
    int qt_g = qt * 4 + b;

    float mc[NS];
    float M = -1e30f;
#pragma unroll
    for (int c = 0; c < NS; c++) {
        mc[c] = mP[(qt_g * NS + c) * 32 + qr];
        M = fmaxf(M, mc[c]);
    }
    float num = 0.f, den = 0.f;
#pragma unroll
    for (int c = 0; c < NS; c++) {
        float wgt = __expf(mc[c] - M);
        den += wgt * lP[(qt_g * NS + c) * 32 + qr];
        num += wgt * bf2f(accP[(size_t)(qt_g * NS + c) * 2048 + qr * 64 + h]);
    }
    out[g] = num / den;
}

// ---------------------------------------------------------------------------
extern "C" void kernel_launch(void* const* d_in, const int* in_sizes, int n_in,
                              void* d_out, int out_size, void* d_ws, size_t ws_size,
                              hipStream_t stream) {
    const float* x  = (const float*)d_in[0];
    const float* Wq = (const float*)d_in[1];
    const float* Wk = (const float*)d_in[2];
    const float* Wv = (const float*)d_in[3];
    float* out = (float*)d_out;

    char* ws = (char*)d_ws;
    unsigned short* Qs = (unsigned short*)(ws);                   // 2 MB @ 0
    unsigned short* Ks = (unsigned short*)(ws + (2u << 20));      // 2 MB @ 2M
    unsigned short* Vt = (unsigned short*)(ws + (4u << 20));      // 2 MB @ 4M
    unsigned short* Wt = (unsigned short*)(ws + (6u << 20));      // 384 KB @ 6M
    unsigned short* accP = (unsigned short*)(ws + (8u << 20));    // 8 MB @ 8M (2048 tasks x 4KB bf16)
    float* mP = (float*)(ws + (24u << 20));                       // 256 KB @ 24M
    float* lP = (float*)(ws + (24u << 20) + (512u << 10));        // 256 KB

    prep_w<<<768, 256, 0, stream>>>(Wq, Wk, Wv, Wt);
    projt<<<1024, 256, 0, stream>>>(x, Wt, Qs, Ks, Vt);

    if (ws_size >= (25u << 20)) {
        attn<4><<<2048, 64, 0, stream>>>(Qs, Ks, Vt, out, accP, mP, lP);
        combine<4><<<4096, 256, 0, stream>>>(accP, mP, lP, out);
    } else {
        attn<1><<<512, 64, 0, stream>>>(Qs, Ks, Vt, out, accP, mP, lP);
    }
}

// Round 25
// 61.328 us; speedup vs baseline: 1.1475x; 1.0467x over previous
//
#include <hip/hip_runtime.h>
#include <hip/hip_bf16.h>

typedef __attribute__((ext_vector_type(8))) short short8;
typedef __attribute__((ext_vector_type(4))) float f32x4;

#define MFMA16(a, b, c) __builtin_amdgcn_mfma_f32_16x16x32_bf16((a), (b), (c), 0, 0, 0)

// scalar round-to-nearest-even f32 -> bf16 bits (proven rounds 1/3/6)
__device__ inline unsigned short f2bf(float f) {
    union { float f; unsigned int u; } v;
    v.f = f;
    unsigned int u = v.u;
    return (unsigned short)((u + 0x7fffu + ((u >> 16) & 1u)) >> 16);
}

__device__ inline float bf2f(unsigned short u) {
    union { unsigned int u; float f; } v;
    v.u = ((unsigned int)u) << 16;
    return v.f;
}

// ---------------------------------------------------------------------------
// FRAGMENT-ORDER LAYOUTS (proven round 18).
// ---------------------------------------------------------------------------
__device__ inline size_t WF(int n, int c) {
    return ((((size_t)(n >> 4)) * 32 + (c >> 5)) * 64 + ((c >> 3) & 3) * 16 + (n & 15)) * 8 + (c & 7);
}
__device__ inline size_t QKF(int q, int h) {
    return ((((size_t)(q >> 4)) * 2 + (h >> 5)) * 64 + ((h >> 3) & 3) * 16 + (q & 15)) * 8 + (h & 7);
}
__device__ inline size_t VF(int h, int t) {
    return ((((size_t)(h >> 4)) * 128 + (t >> 5)) * 64 + ((t >> 3) & 3) * 16 + (h & 15)) * 8 + (t & 7);
}

// ---------------------------------------------------------------------------
// prep_w: Wt in fragment order. n in [0,192): 0..63 Wq (pre-scaled 1/8),
// 64..127 Wk, 128..191 Wv
// ---------------------------------------------------------------------------
__global__ __launch_bounds__(256) void prep_w(const float* __restrict__ Wq,
                                              const float* __restrict__ Wk,
                                              const float* __restrict__ Wv,
                                              unsigned short* __restrict__ Wt) {
    int idx = blockIdx.x * 256 + threadIdx.x;
    if (idx >= 192 * 1024) return;
    int n = idx >> 10;
    int c = idx & 1023;
    const float* W = (n < 64) ? Wq : ((n < 128) ? Wk : Wv);
    float v = W[c * 64 + (n & 63)];
    if (n < 64) v *= 0.125f;  // fold 1/sqrt(head_size) into Wq
    Wt[WF(n, c)] = f2bf(v);
}

// ---------------------------------------------------------------------------
// projt: REG-STAGED SLAB PIPELINE, 32-ROW tiles (512 blocks x 4 waves).
// Halves W L2 re-read traffic vs 16-row (384 MB -> 192 MB). Slab = 32 rows
// x 64 cols f32 (8 KB); 16 slabs; ring[2] in LDS (16 KB). Slab t+2 in regs
// while slab t computes; raw s_barrier + lgkm-only fence -> global loads
// never drained. Swizzle chunk^(row&15) both sides (read: row&15 == lr for
// both row-groups).
// ---------------------------------------------------------------------------
__global__ __launch_bounds__(256, 4) void projt(const float* __restrict__ x,
                                                const unsigned short* __restrict__ Wt,
                                                unsigned short* __restrict__ Qs,
                                                unsigned short* __restrict__ Ks,
                                                unsigned short* __restrict__ Vt) {
    __shared__ __align__(16) float xbuf[2][32 * 64];  // ring of 2 slabs, 16 KB

    const int tid = threadIdx.x;
    const int w = tid >> 6;
    const int lane = tid & 63;
    const int lr = lane & 15;
    const int lg = lane >> 4;
    const int t0 = blockIdx.x * 32;

    // wave w stages slab rows [w*8, w*8+8): lane covers row w*8+j*4+(lane>>4),
    // 16B-chunk (lane&15) of the row's 16 chunks (256 B/row).
    const int sr0 = w * 8 + (lane >> 4);  // + j*4
    const int sch = lane & 15;

#define LOADSLAB(v, sl)                                                        \
    {                                                                          \
        const uint4* xr = (const uint4*)(x + (size_t)(t0) * 1024 + (sl) * 64); \
        v[0] = xr[(size_t)(sr0) * 256 + sch];                                  \
        v[1] = xr[(size_t)(sr0 + 4) * 256 + sch];                              \
    }

#define DSWRITE(buf, v)                                                        \
    {                                                                          \
        _Pragma("unroll")                                                      \
        for (int j = 0; j < 2; j++) {                                          \
            int row = sr0 + j * 4;                                             \
            int l = sch ^ (row & 15);                                          \
            *(uint4*)&xbuf[buf][row * 64 + l * 4] = v[j];                      \
        }                                                                      \
    }

    // prologue: slab0 -> ring[0]; slab1 -> regs
    uint4 vc[2], vn[2];
    LOADSLAB(vc, 0);
    DSWRITE(0, vc);  // compiler waits vmcnt for vc before ds_write
    LOADSLAB(vc, 1);

    f32x4 acc[2][3];
#pragma unroll
    for (int rg = 0; rg < 2; rg++)
#pragma unroll
        for (int i = 0; i < 3; i++) acc[rg][i] = (f32x4){0.f, 0.f, 0.f, 0.f};

#pragma unroll
    for (int t = 0; t < 16; ++t) {
        if (t + 2 < 16) LOADSLAB(vn, t + 2);

        asm volatile("s_waitcnt lgkmcnt(0)" ::: "memory");
        __builtin_amdgcn_sched_barrier(0);
        __builtin_amdgcn_s_barrier();   // all waves done reading ring[(t+1)&1]
        __builtin_amdgcn_sched_barrier(0);

        if (t + 1 < 16) DSWRITE((t + 1) & 1, vc);  // publish slab t+1

        // ---- compute slab t from ring[t&1] (2 h-steps of 32 cols) ----
        const float* xb = &xbuf[t & 1][0];
#pragma unroll
        for (int h = 0; h < 2; h++) {
            short8 bfr[3];
#pragma unroll
            for (int nt = 0; nt < 3; nt++)
                bfr[nt] = *(const short8*)(Wt +
                    (((size_t)(w * 3 + nt) * 32 + (t * 2 + h)) * 64 + lane) * 8);
            int cb = h * 8 + lg * 2;  // within-slab 16B-chunk (0..15)
            int l0 = cb ^ lr;
            int l1 = (cb + 1) ^ lr;
            short8 a[2];
#pragma unroll
            for (int rg = 0; rg < 2; rg++) {
                int row = rg * 16 + lr;
                float4 a0 = *(const float4*)&xb[row * 64 + l0 * 4];
                float4 a1 = *(const float4*)&xb[row * 64 + l1 * 4];
                short8 av;
                av[0] = (short)f2bf(a0.x); av[1] = (short)f2bf(a0.y);
                av[2] = (short)f2bf(a0.z); av[3] = (short)f2bf(a0.w);
                av[4] = (short)f2bf(a1.x); av[5] = (short)f2bf(a1.y);
                av[6] = (short)f2bf(a1.z); av[7] = (short)f2bf(a1.w);
                a[rg] = av;
            }
#pragma unroll
            for (int rg = 0; rg < 2; rg++)
#pragma unroll
                for (int nt = 0; nt < 3; nt++)
                    acc[rg][nt] = MFMA16(a[rg], bfr[nt], acc[rg][nt]);
        }

        if (t + 2 < 16) { vc[0] = vn[0]; vc[1] = vn[1]; }  // guarded rotate
    }

    // epilogue: D col = lr -> n, row = lg*4+r (within rg) -> t; fragment-order
    const int nbase = w * 48;
#pragma unroll
    for (int rg = 0; rg < 2; rg++) {
#pragma unroll
        for (int nt = 0; nt < 3; nt++) {
#pragma unroll
            for (int r = 0; r < 4; r++) {
                int n = nbase + nt * 16 + lr;
                int tq = t0 + rg * 16 + lg * 4 + r;
                int b = tq >> 12;
                int qq = tq & 4095;
                unsigned short val = f2bf(acc[rg][nt][r]);
                if (n < 64) {
                    Qs[(size_t)b * 262144 + QKF(qq, n)] = val;
                } else if (n < 128) {
                    Ks[(size_t)b * 262144 + QKF(qq, n - 64)] = val;
                } else {
                    Vt[(size_t)b * 262144 + VF(n - 128, qq)] = val;
                }
            }
        }
    }
}

// ---------------------------------------------------------------------------
// attn<NS>: causal flash attention, swapped QK^T (S^T = K*Q), QBLK=32,
// KVBLK=64, 1 wave/block, KV split into NS chunks. Barrier-free inner loop
// (single-wave blocks; lgkmcnt fence only). All Q/K/V loads are contiguous
// 1KB fragment-order wave-loads. (Identical to rounds 18-24.)
// ---------------------------------------------------------------------------
#define SROW 72  // P-tile row stride in halfwords (144 B/row)

template <int NS>
__global__ __launch_bounds__(64) void attn(const unsigned short* __restrict__ Qs,
                                           const unsigned short* __restrict__ Ks,
                                           const unsigned short* __restrict__ Vt,
                                           float* __restrict__ out,
                                           unsigned short* __restrict__ accP,
                                           float* __restrict__ mP,
                                           float* __restrict__ lP) {
    __shared__ unsigned short pl[32 * SROW];  // 32 q-rows x 64 kv-cols

    const int ntasks = 512 * NS;
    int raw = ntasks - 1 - blockIdx.x;  // longest scans first
    int qt_g = raw / NS;
    int c = raw - qt_g * NS;
    int qt = qt_g >> 2;
    int b = qt_g & 3;
    int q0 = qt * 32;

    int lane = threadIdx.x;
    int lr = lane & 15;
    int lg = lane >> 4;

    const unsigned short* Qb = Qs + (size_t)b * 262144;
    const unsigned short* Kb = Ks + (size_t)b * 262144;
    const unsigned short* Vb = Vt + (size_t)b * 262144;

    short8 qf[2][2];
#pragma unroll
    for (int qs = 0; qs < 2; qs++)
#pragma unroll
        for (int kh = 0; kh < 2; kh++)
            qf[qs][kh] = *(const short8*)(Qb +
                (((size_t)((q0 >> 4) + qs) * 2 + kh) * 64 + lane) * 8);

    f32x4 acc[4][2];  // [ht][qs]
#pragma unroll
    for (int i = 0; i < 4; i++)
#pragma unroll
        for (int qs = 0; qs < 2; qs++) acc[i][qs] = (f32x4){0.f, 0.f, 0.f, 0.f};
    float m[2] = {-1e30f, -1e30f};
    float l[2] = {0.f, 0.f};  // LANE-PARTIAL

    int nt = (q0 + 95) >> 6;  // ceil((q0+32)/64)
    int tb = (c * nt) / NS;
    int te = ((c + 1) * nt) / NS;

    // ---- preload K fragments for first tile ----
    short8 kf[4][2];
    if (tb < te) {
#pragma unroll
        for (int t = 0; t < 4; t++)
#pragma unroll
            for (int half = 0; half < 2; half++)
                kf[t][half] = *(const short8*)(Kb +
                    (((size_t)((tb * 64) >> 4) + t) * 2 + half) * 512 + lane * 8);
    }

    for (int t64 = tb; t64 < te; ++t64) {
        int kv0 = t64 * 64;

        // ---- S^T = K Q (consumes kf) ----
        f32x4 s[4][2];
#pragma unroll
        for (int t = 0; t < 4; t++)
#pragma unroll
            for (int qs = 0; qs < 2; qs++) {
                f32x4 z = (f32x4){0.f, 0.f, 0.f, 0.f};
                z = MFMA16(kf[t][0], qf[qs][0], z);
                z = MFMA16(kf[t][1], qf[qs][1], z);
                s[t][qs] = z;
            }

        // ---- issue V loads (contiguous 1KB each; in flight thru softmax) ----
        short8 vf[4][2];
#pragma unroll
        for (int ht = 0; ht < 4; ht++)
#pragma unroll
            for (int half = 0; half < 2; half++)
                vf[ht][half] = *(const short8*)(Vb +
                    (((size_t)ht * 128 + (kv0 >> 5) + half) * 64 + lane) * 8);

        // ---- reload kf for NEXT tile (latency hides under softmax+PV) ----
        if (t64 + 1 < te) {
            int kvn = (t64 + 1) * 64;
#pragma unroll
            for (int t = 0; t < 4; t++)
#pragma unroll
                for (int half = 0; half < 2; half++)
                    kf[t][half] = *(const short8*)(Kb +
                        (((size_t)(kvn >> 4) + t) * 2 + half) * 512 + lane * 8);
        }

        // ---- causal mask (only the straddling tile needs it) ----
        if (kv0 + 63 > q0) {
#pragma unroll
            for (int t = 0; t < 4; t++)
#pragma unroll
                for (int qs = 0; qs < 2; qs++)
#pragma unroll
                    for (int r = 0; r < 4; r++) {
                        int kv = kv0 + t * 16 + lg * 4 + r;
                        if (kv > q0 + qs * 16 + lr) s[t][qs][r] = -1e30f;
                    }
        }

        // ---- lane-local tile max (for defer-max check) ----
        float pmax[2] = {-1e30f, -1e30f};
#pragma unroll
        for (int t = 0; t < 4; t++)
#pragma unroll
            for (int qs = 0; qs < 2; qs++)
#pragma unroll
                for (int r = 0; r < 4; r++) pmax[qs] = fmaxf(pmax[qs], s[t][qs][r]);

        int ok = (pmax[0] <= m[0] + 8.0f) && (pmax[1] <= m[1] + 8.0f);
        if (!__all(ok)) {
            float alpha[2];
#pragma unroll
            for (int qs = 0; qs < 2; qs++) {
                float mx = pmax[qs];
                mx = fmaxf(mx, __shfl_xor(mx, 16));
                mx = fmaxf(mx, __shfl_xor(mx, 32));
                float mn = fmaxf(m[qs], mx);
                alpha[qs] = __expf(m[qs] - mn);
                m[qs] = mn;
                l[qs] *= alpha[qs];
            }
            float ar[2][4];
#pragma unroll
            for (int qs = 0; qs < 2; qs++)
#pragma unroll
                for (int r = 0; r < 4; r++) ar[qs][r] = __shfl(alpha[qs], lg * 4 + r);
#pragma unroll
            for (int ht = 0; ht < 4; ht++)
#pragma unroll
                for (int qs = 0; qs < 2; qs++)
#pragma unroll
                    for (int r = 0; r < 4; r++) acc[ht][qs][r] *= ar[qs][r];
        }

        // ---- exp + lane-partial l accumulation ----
#pragma unroll
        for (int t = 0; t < 4; t++)
#pragma unroll
            for (int qs = 0; qs < 2; qs++)
#pragma unroll
                for (int r = 0; r < 4; r++) {
                    float e = __expf(s[t][qs][r] - m[qs]);
                    s[t][qs][r] = e;
                    l[qs] += e;
                }

        // ---- pack P -> LDS (single-wave: lgkmcnt fence only, rule #18) ----
#pragma unroll
        for (int qs = 0; qs < 2; qs++)
#pragma unroll
            for (int t = 0; t < 4; t++) {
                uint2 uu;
                uu.x = (unsigned)f2bf(s[t][qs][0]) | ((unsigned)f2bf(s[t][qs][1]) << 16);
                uu.y = (unsigned)f2bf(s[t][qs][2]) | ((unsigned)f2bf(s[t][qs][3]) << 16);
                *(uint2*)&pl[(qs * 16 + lr) * SROW + t * 16 + lg * 4] = uu;
            }
        asm volatile("s_waitcnt lgkmcnt(0)" ::: "memory");
        __builtin_amdgcn_sched_barrier(0);
        short8 pa[2][2];
#pragma unroll
        for (int qs = 0; qs < 2; qs++)
#pragma unroll
            for (int half = 0; half < 2; half++)
                pa[qs][half] = *(const short8*)&pl[(qs * 16 + lr) * SROW +
                                                   half * 32 + lg * 8];

        // ---- O += P V ----
#pragma unroll
        for (int ht = 0; ht < 4; ht++)
#pragma unroll
            for (int qs = 0; qs < 2; qs++) {
                acc[ht][qs] = MFMA16(pa[qs][0], vf[ht][0], acc[ht][qs]);
                acc[ht][qs] = MFMA16(pa[qs][1], vf[ht][1], acc[ht][qs]);
            }
    }

    // ---- epilogue: reduce lane-partial l across the 4 lg groups ----
    float lt[2];
#pragma unroll
    for (int qs = 0; qs < 2; qs++) {
        float v = l[qs];
        v += __shfl_xor(v, 16);
        v += __shfl_xor(v, 32);
        lt[qs] = v;
    }

    if (NS == 1) {
        float rl[2][4];
#pragma unroll
        for (int qs = 0; qs < 2; qs++)
#pragma unroll
            for (int r = 0; r < 4; r++) rl[qs][r] = 1.0f / __shfl(lt[qs], lg * 4 + r);
#pragma unroll
        for (int ht = 0; ht < 4; ht++)
#pragma unroll
            for (int qs = 0; qs < 2; qs++)
#pragma unroll
                for (int r = 0; r < 4; r++) {
                    size_t o = ((size_t)b * 4096 + q0 + qs * 16 + lg * 4 + r) * 64 +
                               ht * 16 + lr;
                    out[o] = acc[ht][qs][r] * rl[qs][r];
                }
    } else {
        int tidx = qt_g * NS + c;
        unsigned short* ap = accP + (size_t)tidx * 2048;
#pragma unroll
        for (int ht = 0; ht < 4; ht++)
#pragma unroll
            for (int qs = 0; qs < 2; qs++)
#pragma unroll
                for (int r = 0; r < 4; r++)
                    ap[(qs * 16 + lg * 4 + r) * 64 + ht * 16 + lr] =
                        f2bf(acc[ht][qs][r]);
        if (lane < 16) {
#pragma unroll
            for (int qs = 0; qs < 2; qs++) {
                mP[tidx * 32 + qs * 16 + lane] = m[qs];
                lP[tidx * 32 + qs * 16 + lane] = lt[qs];
            }
        }
    }
}

// ---------------------------------------------------------------------------
// combine<NS>: out[row][h] = sum_c e^{m_c-M} acc_c / sum_c e^{m_c-M} l_c
// (bf16 partials)
// ---------------------------------------------------------------------------
template <int NS>
__global__ __launch_bounds__(256) void combine(const unsigned short* __restrict__ accP,
                                               const float* __restrict__ mP,
                                               const float* __restrict__ lP,
                                               float* __restrict__ out) {
    int g = blockIdx.x * 256 + threadIdx.x;  // 0 .. 1M-1
    int h = g & 63;
    int row = g >> 6;       // b*4096 + t
    int b = row >> 12;
    int t = row & 4095;
    int qt = t >> 5;
    int qr = t & 31;
    int qt_g = qt * 4 + b;

    float mc[NS];
    float M = -1e30f;
#pragma unroll
    for (int c = 0; c < NS; c++) {
        mc[c] = mP[(qt_g * NS + c) * 32 + qr];
        M = fmaxf(M, mc[c]);
    }
    float num = 0.f, den = 0.f;
#pragma unroll
    for (int c = 0; c < NS; c++) {
        float wgt = __expf(mc[c] - M);
        den += wgt * lP[(qt_g * NS + c) * 32 + qr];
        num += wgt * bf2f(accP[(size_t)(qt_g * NS + c) * 2048 + qr * 64 + h]);
    }
    out[g] = num / den;
}

// ---------------------------------------------------------------------------
extern "C" void kernel_launch(void* const* d_in, const int* in_sizes, int n_in,
                              void* d_out, int out_size, void* d_ws, size_t ws_size,
                              hipStream_t stream) {
    const float* x  = (const float*)d_in[0];
    const float* Wq = (const float*)d_in[1];
    const float* Wk = (const float*)d_in[2];
    const float* Wv = (const float*)d_in[3];
    float* out = (float*)d_out;

    char* ws = (char*)d_ws;
    unsigned short* Qs = (unsigned short*)(ws);                   // 2 MB @ 0
    unsigned short* Ks = (unsigned short*)(ws + (2u << 20));      // 2 MB @ 2M
    unsigned short* Vt = (unsigned short*)(ws + (4u << 20));      // 2 MB @ 4M
    unsigned short* Wt = (unsigned short*)(ws + (6u << 20));      // 384 KB @ 6M
    unsigned short* accP = (unsigned short*)(ws + (8u << 20));    // 8 MB @ 8M (2048 tasks x 4KB bf16)
    float* mP = (float*)(ws + (24u << 20));                       // 256 KB @ 24M
    float* lP = (float*)(ws + (24u << 20) + (512u << 10));        // 256 KB

    prep_w<<<768, 256, 0, stream>>>(Wq, Wk, Wv, Wt);
    projt<<<512, 256, 0, stream>>>(x, Wt, Qs, Ks, Vt);

    if (ws_size >= (25u << 20)) {
        attn<4><<<2048, 64, 0, stream>>>(Qs, Ks, Vt, out, accP, mP, lP);
        combine<4><<<4096, 256, 0, stream>>>(accP, mP, lP, out);
    } else {
        attn<1><<<512, 64, 0, stream>>>(Qs, Ks, Vt, out, accP, mP, lP);
    }
}